// Round 1
// baseline (870.916 us; speedup 1.0000x reference)
//
#include <hip/hip_runtime.h>
#include <math.h>

#define NTHR 256

__device__ __forceinline__ int reflect32(int v) {
  if (v < 0) v = -v;
  if (v > 31) v = 62 - v;
  return v;
}

// ---------- f32 2D DFT (N x N), two matmul passes over LDS ----------
// io: input and output (in-place). tmp: scratch. tw[j] = exp(-2*pi*i*j/N).
template<int N, bool INV>
__device__ void dft2d(float2* io, float2* tmp, const float2* tw, int tid) {
  __syncthreads();
  // pass 1: tmp[r][k] = sum_c io[r][c] * W^(k*c)
  for (int o = tid; o < N * N; o += NTHR) {
    int r = o / N, k = o - r * N;
    float re = 0.f, im = 0.f;
    int idx = 0;
    for (int c = 0; c < N; ++c) {
      float2 v = io[r * N + c];
      float2 w = tw[idx];
      float wy = INV ? -w.y : w.y;
      re += v.x * w.x - v.y * wy;
      im += v.x * wy + v.y * w.x;
      idx += k; if (idx >= N) idx -= N;
    }
    tmp[o] = make_float2(re, im);
  }
  __syncthreads();
  // pass 2: io[k1][k2] = sum_r tmp[r][k2] * W^(k1*r)
  const float scale = INV ? (1.f / (float)(N * N)) : 1.f;
  for (int o = tid; o < N * N; o += NTHR) {
    int k1 = o / N, k2 = o - k1 * N;
    float re = 0.f, im = 0.f;
    int idx = 0;
    for (int r = 0; r < N; ++r) {
      float2 v = tmp[r * N + k2];
      float2 w = tw[idx];
      float wy = INV ? -w.y : w.y;
      re += v.x * w.x - v.y * wy;
      im += v.x * wy + v.y * w.x;
      idx += k1; if (idx >= N) idx -= N;
    }
    io[o] = make_float2(re * scale, im * scale);
  }
  __syncthreads();
}

// ---------- f64 2D DFT, N=40, forward only (filter generation) ----------
__device__ void dft2d40_f64(double2* io, double2* tmp, const double2* tw, int tid) {
  __syncthreads();
  for (int o = tid; o < 1600; o += NTHR) {
    int r = o / 40, k = o - 40 * r;
    double re = 0.0, im = 0.0;
    int idx = 0;
    for (int c = 0; c < 40; ++c) {
      double2 v = io[r * 40 + c];
      double2 w = tw[idx];
      re += v.x * w.x - v.y * w.y;
      im += v.x * w.y + v.y * w.x;
      idx += k; if (idx >= 40) idx -= 40;
    }
    tmp[o] = make_double2(re, im);
  }
  __syncthreads();
  for (int o = tid; o < 1600; o += NTHR) {
    int k1 = o / 40, k2 = o - 40 * k1;
    double re = 0.0, im = 0.0;
    int idx = 0;
    for (int r = 0; r < 40; ++r) {
      double2 v = tmp[r * 40 + k2];
      double2 w = tw[idx];
      re += v.x * w.x - v.y * w.y;
      im += v.x * w.y + v.y * w.x;
      idx += k1; if (idx >= 40) idx -= 40;
    }
    io[o] = make_double2(re, im);
  }
  __syncthreads();
}

__device__ __forceinline__ void init_tw(float2* tw, int N, int tid) {
  for (int j = tid; j < N; j += NTHR) {
    float s, c;
    sincosf(-2.0f * (float)M_PI * (float)j / (float)N, &s, &c);
    tw[j] = make_float2(c, s);
  }
}

// ---------- Kernel 1: Morlet filter bank (double precision, on device) ----------
// filt layout (floats): phi0[1600] | phi1[400] | psi0[8*1600] | psi1[8*1600]
__global__ __launch_bounds__(NTHR) void k_filters(float* __restrict__ filt) {
  const int fid = blockIdx.x;   // 0=phi, 1..8=psi0 t, 9..16=psi1 t
  const int tid = threadIdx.x;

  __shared__ double2 WV[1600];
  __shared__ float   EV[1600];
  __shared__ double2 TMP[1600];
  __shared__ double2 twd[40];
  __shared__ double  sred[3][4];
  __shared__ double  Kc[2];

  double sigma, theta, xi, slant; int morlet; int outOff;
  if (fid == 0)      { sigma = 3.2; theta = 0.0; xi = 0.0;                  slant = 1.0; morlet = 0; outOff = 0; }
  else if (fid <= 8) { int t = fid - 1; sigma = 0.8; theta = (3 - t) * M_PI / 8.0; xi = 3.0 * M_PI / 4.0; slant = 0.5; morlet = 1; outOff = 2000 + t * 1600; }
  else               { int t = fid - 9; sigma = 1.6; theta = (3 - t) * M_PI / 8.0; xi = 3.0 * M_PI / 8.0; slant = 0.5; morlet = 1; outOff = 14800 + t * 1600; }

  const double ct = cos(theta), st = sin(theta);
  const double sl2 = slant * slant;
  const double inv2s = 1.0 / (2.0 * sigma * sigma);
  const double ca = (ct * ct + sl2 * st * st) * inv2s;
  const double cb = (ct * st * (1.0 - sl2)) * inv2s;   // off-diagonal (each); arg uses 2*cb
  const double cd = (st * st + sl2 * ct * ct) * inv2s;
  const double norm = 2.0 * M_PI * sigma * sigma / slant;

  double swr = 0.0, swi = 0.0, ser = 0.0;
  for (int o = tid; o < 1600; o += NTHR) {
    int xr = o / 40, yc = o - 40 * xr;   // xr = first axis (mgrid xx)
    double wr = 0.0, wi = 0.0, er = 0.0;
    for (int ex = -2; ex <= 2; ++ex) {
      for (int ey = -2; ey <= 2; ++ey) {
        double xg = xr + ex * 40.0, yg = yc + ey * 40.0;
        double e = exp(-(ca * xg * xg + 2.0 * cb * xg * yg + cd * yg * yg));
        double ai = xi * (xg * ct + yg * st);
        double s, c;
        sincos(ai, &s, &c);
        wr += e * c; wi += e * s; er += e;
      }
    }
    wr /= norm; wi /= norm; er /= norm;
    WV[o] = make_double2(wr, wi);
    EV[o] = (float)er;
    swr += wr; swi += wi; ser += er;
  }
  // block-wide sums (wave shfl + LDS cross-wave)
  for (int off = 32; off > 0; off >>= 1) {
    swr += __shfl_down(swr, off);
    swi += __shfl_down(swi, off);
    ser += __shfl_down(ser, off);
  }
  int lane = tid & 63, w = tid >> 6;
  if (lane == 0) { sred[0][w] = swr; sred[1][w] = swi; sred[2][w] = ser; }
  __syncthreads();
  if (tid == 0) {
    double A = 0, B = 0, C = 0;
    for (int i = 0; i < 4; ++i) { A += sred[0][i]; B += sred[1][i]; C += sred[2][i]; }
    Kc[0] = A / C; Kc[1] = B / C;
  }
  __syncthreads();
  if (morlet) {
    for (int o = tid; o < 1600; o += NTHR) {
      double e = (double)EV[o];
      WV[o].x -= Kc[0] * e;
      WV[o].y -= Kc[1] * e;
    }
  }
  for (int j = tid; j < 40; j += NTHR) {
    double s, c;
    sincos(-2.0 * M_PI * (double)j / 40.0, &s, &c);
    twd[j] = make_double2(c, s);
  }
  dft2d40_f64(WV, TMP, twd, tid);   // entry sync covers pending writes
  for (int o = tid; o < 1600; o += NTHR) filt[outOff + o] = (float)WV[o].x;
  if (fid == 0) {
    __syncthreads();
    // phi1 = periodize(phi0, 1): 2x2 spectral fold
    for (int q = tid; q < 400; q += NTHR) {
      int q1 = q / 20, q2 = q - 20 * q1;
      double v = 0.25 * (WV[q1 * 40 + q2].x + WV[(q1 + 20) * 40 + q2].x +
                         WV[q1 * 40 + (q2 + 20)].x + WV[(q1 + 20) * 40 + (q2 + 20)].x);
      filt[1600 + q] = (float)v;
    }
  }
}

// ---------- Kernel 2: pad + fft2(xp) -> xf; S0 ----------
__global__ __launch_bounds__(NTHR) void k_fftx(const float* __restrict__ x,
                                               const float* __restrict__ filt,
                                               float2* __restrict__ xf_g,
                                               float* __restrict__ f) {
  const int bc = blockIdx.x;            // b*3 + c
  const int b = bc / 3, c = bc - 3 * b;
  const int tid = threadIdx.x;

  __shared__ float2 A[1600], T[1600];
  __shared__ float2 P[100], Q[100];
  __shared__ float2 tw40[40], tw10[10];

  init_tw(tw40, 40, tid);
  init_tw(tw10, 10, tid);

  const float* xb = x + (size_t)bc * 1024;
  for (int o = tid; o < 1600; o += NTHR) {
    int i = o / 40, j = o - 40 * i;
    int si = reflect32(i - 4), sj = reflect32(j - 4);
    A[o] = make_float2(xb[si * 32 + sj], 0.f);
  }
  dft2d<40, false>(A, T, tw40, tid);
  for (int o = tid; o < 1600; o += NTHR) xf_g[(size_t)bc * 1600 + o] = A[o];

  // S0 = ifft2_10( fold4( xf * phi0 ) ), real, [1:-1]
  const float* phi0 = filt;
  for (int q = tid; q < 100; q += NTHR) {
    int q1 = q / 10, q2 = q - 10 * q1;
    float re = 0.f, im = 0.f;
    for (int a2 = 0; a2 < 4; ++a2)
      for (int b2 = 0; b2 < 4; ++b2) {
        int idx = (q1 + 10 * a2) * 40 + (q2 + 10 * b2);
        float ph = phi0[idx];
        re += A[idx].x * ph; im += A[idx].y * ph;
      }
    P[q] = make_float2(re * (1.f / 16.f), im * (1.f / 16.f));
  }
  dft2d<10, true>(P, Q, tw10, tid);
  float* fb = f + (size_t)b * 15552 + c * 5184;
  for (int o = tid; o < 64; o += NTHR) {
    int i = o >> 3, j = o & 7;
    fb[o] = P[(i + 1) * 10 + (j + 1)].x;   // idx 0
  }
}

// ---------- Kernel 3: per (b,c,t): U1a, S1a, U1b, S1b, 8x S2 ----------
__global__ __launch_bounds__(NTHR) void k_main(const float2* __restrict__ xf_g,
                                               const float* __restrict__ filt,
                                               float* __restrict__ f) {
  const int blk = blockIdx.x;           // 384*8
  const int t = blk & 7;
  const int bc = blk >> 3;
  const int b = bc / 3, c = bc - 3 * b;
  const int tid = threadIdx.x;

  __shared__ float2 X[1600];            // xf
  __shared__ float2 A[1600];            // working 40x40
  __shared__ float2 T[1600];            // DFT scratch
  __shared__ float2 C[400], D[400];     // 20x20
  __shared__ float2 P[100], Q[100];     // 10x10
  __shared__ float2 tw40[40], tw20[20], tw10[10];

  const float* phi0 = filt;
  const float* phi1 = filt + 1600;
  const float* psi0 = filt + 2000;
  const float* psi1 = filt + 14800;

  init_tw(tw40, 40, tid);
  init_tw(tw20, 20, tid);
  init_tw(tw10, 10, tid);

  const float2* xf = xf_g + (size_t)bc * 1600;
  const float* ps0 = psi0 + t * 1600;
  for (int o = tid; o < 1600; o += NTHR) {
    float2 v = xf[o];
    X[o] = v;
    float p = ps0[o];
    A[o] = make_float2(v.x * p, v.y * p);
  }
  // Za = ifft2(xf * psi0[t]); U1a = |Za|
  dft2d<40, true>(A, T, tw40, tid);
  for (int o = tid; o < 1600; o += NTHR) {
    float2 z = A[o];
    A[o] = make_float2(sqrtf(z.x * z.x + z.y * z.y), 0.f);
  }
  // Ua_f = fft2(U1a)
  dft2d<40, false>(A, T, tw40, tid);

  float* fb = f + (size_t)b * 15552 + c * 5184;

  // S1a = ifft2_10( fold4( Ua_f * phi0 ) )
  for (int q = tid; q < 100; q += NTHR) {
    int q1 = q / 10, q2 = q - 10 * q1;
    float re = 0.f, im = 0.f;
    for (int a2 = 0; a2 < 4; ++a2)
      for (int b2 = 0; b2 < 4; ++b2) {
        int idx = (q1 + 10 * a2) * 40 + (q2 + 10 * b2);
        float ph = phi0[idx];
        re += A[idx].x * ph; im += A[idx].y * ph;
      }
    P[q] = make_float2(re * (1.f / 16.f), im * (1.f / 16.f));
  }
  dft2d<10, true>(P, Q, tw10, tid);
  for (int o = tid; o < 64; o += NTHR) {
    int i = o >> 3, j = o & 7;
    fb[(1 + t) * 64 + o] = P[(i + 1) * 10 + (j + 1)].x;
  }

  // U1b = |ifft2_20( fold2( xf * psi1[t] ) )| ; S1b
  const float* ps1t = psi1 + t * 1600;
  for (int q = tid; q < 400; q += NTHR) {
    int q1 = q / 20, q2 = q - 20 * q1;
    float re = 0.f, im = 0.f;
    for (int a2 = 0; a2 < 2; ++a2)
      for (int b2 = 0; b2 < 2; ++b2) {
        int idx = (q1 + 20 * a2) * 40 + (q2 + 20 * b2);
        float ph = ps1t[idx];
        float2 v = X[idx];
        re += v.x * ph; im += v.y * ph;
      }
    C[q] = make_float2(re * 0.25f, im * 0.25f);
  }
  dft2d<20, true>(C, D, tw20, tid);
  for (int o = tid; o < 400; o += NTHR) {
    float2 z = C[o];
    C[o] = make_float2(sqrtf(z.x * z.x + z.y * z.y), 0.f);
  }
  dft2d<20, false>(C, D, tw20, tid);
  for (int q = tid; q < 100; q += NTHR) {
    int q1 = q / 10, q2 = q - 10 * q1;
    float re = 0.f, im = 0.f;
    for (int a2 = 0; a2 < 2; ++a2)
      for (int b2 = 0; b2 < 2; ++b2) {
        int idx20 = (q1 + 10 * a2) * 20 + (q2 + 10 * b2);
        float ph = phi1[idx20];
        re += C[idx20].x * ph; im += C[idx20].y * ph;
      }
    P[q] = make_float2(re * 0.25f, im * 0.25f);
  }
  dft2d<10, true>(P, Q, tw10, tid);
  for (int o = tid; o < 64; o += NTHR) {
    int i = o >> 3, j = o & 7;
    fb[(9 + t) * 64 + o] = P[(i + 1) * 10 + (j + 1)].x;
  }

  // order 2: for each t2: U2 = |ifft2_20(fold2(Ua_f * psi1[t2]))|; S2
  for (int t2 = 0; t2 < 8; ++t2) {
    const float* ps1 = psi1 + t2 * 1600;
    __syncthreads();
    for (int q = tid; q < 400; q += NTHR) {
      int q1 = q / 20, q2 = q - 20 * q1;
      float re = 0.f, im = 0.f;
      for (int a2 = 0; a2 < 2; ++a2)
        for (int b2 = 0; b2 < 2; ++b2) {
          int idx = (q1 + 20 * a2) * 40 + (q2 + 20 * b2);
          float ph = ps1[idx];
          float2 v = A[idx];
          re += v.x * ph; im += v.y * ph;
        }
      C[q] = make_float2(re * 0.25f, im * 0.25f);
    }
    dft2d<20, true>(C, D, tw20, tid);
    for (int o = tid; o < 400; o += NTHR) {
      float2 z = C[o];
      C[o] = make_float2(sqrtf(z.x * z.x + z.y * z.y), 0.f);
    }
    dft2d<20, false>(C, D, tw20, tid);
    for (int q = tid; q < 100; q += NTHR) {
      int q1 = q / 10, q2 = q - 10 * q1;
      float re = 0.f, im = 0.f;
      for (int a2 = 0; a2 < 2; ++a2)
        for (int b2 = 0; b2 < 2; ++b2) {
          int idx20 = (q1 + 10 * a2) * 20 + (q2 + 10 * b2);
          float ph = phi1[idx20];
          re += C[idx20].x * ph; im += C[idx20].y * ph;
        }
      P[q] = make_float2(re * 0.25f, im * 0.25f);
    }
    dft2d<10, true>(P, Q, tw10, tid);
    for (int o = tid; o < 64; o += NTHR) {
      int i = o >> 3, j = o & 7;
      fb[(17 + t * 8 + t2) * 64 + o] = P[(i + 1) * 10 + (j + 1)].x;
    }
  }
}

// ---------- Kernel 4: BN stats over batch ----------
__global__ __launch_bounds__(NTHR) void k_bn(const float* __restrict__ f,
                                             float* __restrict__ mu,
                                             float* __restrict__ rstd) {
  int col = blockIdx.x * NTHR + threadIdx.x;
  if (col >= 15552) return;
  double s = 0.0, s2 = 0.0;
  for (int b = 0; b < 128; ++b) {
    float v = f[(size_t)b * 15552 + col];
    s += v; s2 += (double)v * v;
  }
  double m = s / 128.0;
  double var = s2 / 128.0 - m * m;
  mu[col] = (float)m;
  rstd[col] = (float)(1.0 / sqrt(var + 1e-5));
}

// ---------- Kernel 5: normalize + relu ----------
__global__ __launch_bounds__(NTHR) void k_norm(const float* __restrict__ f,
                                               const float* __restrict__ mu,
                                               const float* __restrict__ rstd,
                                               const float* __restrict__ gamma,
                                               const float* __restrict__ beta,
                                               float* __restrict__ g) {
  size_t i = (size_t)blockIdx.x * NTHR + threadIdx.x;
  if (i >= (size_t)128 * 15552) return;
  int col = (int)(i % 15552);
  float v = (f[i] - mu[col]) * rstd[col] * gamma[col] + beta[col];
  g[i] = v > 0.f ? v : 0.f;
}

// ---------- Kernel 6: collapsed ToeplitzLike, first 10 outputs ----------
__global__ __launch_bounds__(NTHR) void k_out(const float* __restrict__ g,
                                              const float* __restrict__ Gm,
                                              const float* __restrict__ Hm,
                                              float* __restrict__ out) {
  const int b = blockIdx.x;
  const int tid = threadIdx.x;
  const float* gb = g + (size_t)b * 15552;

  float acc[40];
#pragma unroll
  for (int i = 0; i < 40; ++i) acc[i] = 0.f;

  for (int j = tid; j < 15552; j += NTHR) {
    float h[4];
#pragma unroll
    for (int r = 0; r < 4; ++r) h[r] = Hm[r * 15552 + j];
#pragma unroll
    for (int m = 0; m < 10; ++m) {
      int jm = j + m;
      float gv = (jm < 15552) ? gb[jm] : 0.f;
#pragma unroll
      for (int r = 0; r < 4; ++r) acc[r * 10 + m] += h[r] * gv;
    }
  }
  // reduce 40 accumulators over the block
#pragma unroll
  for (int i = 0; i < 40; ++i)
    for (int off = 32; off > 0; off >>= 1)
      acc[i] += __shfl_down(acc[i], off);

  __shared__ float red[4][40];
  __shared__ float Tm[40];
  int lane = tid & 63, w = tid >> 6;
  if (lane == 0) {
#pragma unroll
    for (int i = 0; i < 40; ++i) red[w][i] = acc[i];
  }
  __syncthreads();
  if (tid < 40) Tm[tid] = red[0][tid] + red[1][tid] + red[2][tid] + red[3][tid];
  __syncthreads();
  if (tid < 10) {
    float y = 0.f;
    for (int r = 0; r < 4; ++r)
      for (int m = 0; m <= tid; ++m)
        y += Gm[r * 15552 + (tid - m)] * Tm[r * 10 + m];
    out[b * 10 + tid] = y;
  }
}

extern "C" void kernel_launch(void* const* d_in, const int* in_sizes, int n_in,
                              void* d_out, int out_size, void* d_ws, size_t ws_size,
                              hipStream_t stream) {
  (void)in_sizes; (void)n_in; (void)out_size; (void)ws_size;
  const float* x     = (const float*)d_in[0];   // (128,3,32,32)
  const float* gamma = (const float*)d_in[1];   // (15552,)
  const float* beta  = (const float*)d_in[2];   // (15552,)
  const float* G     = (const float*)d_in[3];   // (4,15552)
  const float* H     = (const float*)d_in[4];   // (4,15552)
  float* out = (float*)d_out;                   // (128,10)

  float* ws   = (float*)d_ws;
  float* filt = ws;                         // 27600
  float* xf   = filt + 27600;               // 384*1600*2 = 1228800
  float* f    = xf + 1228800;               // 128*15552 = 1990656
  float* g    = f + 1990656;                // 1990656
  float* mu   = g + 1990656;                // 15552
  float* rstd = mu + 15552;                 // 15552

  k_filters<<<17, NTHR, 0, stream>>>(filt);
  k_fftx<<<384, NTHR, 0, stream>>>(x, filt, (float2*)xf, f);
  k_main<<<3072, NTHR, 0, stream>>>((const float2*)xf, filt, f);
  k_bn<<<61, NTHR, 0, stream>>>(f, mu, rstd);
  k_norm<<<7776, NTHR, 0, stream>>>(f, mu, rstd, gamma, beta, g);
  k_out<<<128, NTHR, 0, stream>>>(g, G, H, out);
}

// Round 2
// 492.333 us; speedup vs baseline: 1.7690x; 1.7690x over previous
//
#include <hip/hip_runtime.h>
#include <math.h>

#define NTHR 256

__device__ __forceinline__ int reflect32(int v) {
  if (v < 0) v = -v;
  if (v > 31) v = 62 - v;
  return v;
}

__device__ __forceinline__ void init_tw(float2* tw, int N, int tid) {
  for (int j = tid; j < N; j += NTHR) {
    float s, c;
    sincosf(-2.0f * (float)M_PI * (float)j / (float)N, &s, &c);
    tw[j] = make_float2(c, s);
  }
}

// ---------- Horner DFT passes ----------
// rows: tmp[r][k] = sum_c io[r][c] * x^c, x = tw[k] (conj if INV)
template<int N, int LD, int NK, bool INV>
__device__ __forceinline__ void dft_rows(const float2* __restrict__ io,
                                         float2* __restrict__ tmp,
                                         const float2* __restrict__ tw, int tid) {
  constexpr int G = N / NK;
  if (tid < N * G) {
    const int r = tid / G, kg = tid - G * r;
    float xr[NK], xi[NK], ar[NK], ai[NK];
#pragma unroll
    for (int j = 0; j < NK; ++j) {
      float2 w = tw[kg * NK + j];
      xr[j] = w.x; xi[j] = INV ? -w.y : w.y;
    }
    const float2* row = io + r * LD;
    float2 v = row[N - 1];
#pragma unroll
    for (int j = 0; j < NK; ++j) { ar[j] = v.x; ai[j] = v.y; }
#pragma unroll 2
    for (int c = N - 2; c >= 0; --c) {
      v = row[c];
#pragma unroll
      for (int j = 0; j < NK; ++j) {
        float nr = fmaf(ar[j], xr[j], fmaf(-ai[j], xi[j], v.x));
        float ni = fmaf(ar[j], xi[j], fmaf(ai[j], xr[j], v.y));
        ar[j] = nr; ai[j] = ni;
      }
    }
    float2* orow = tmp + r * LD + kg * NK;
#pragma unroll
    for (int j = 0; j < NK; ++j) orow[j] = make_float2(ar[j], ai[j]);
  }
}

// cols: io[k1][k2] = sum_r tmp[r][k2] * x^r, x = tw[k1] (conj if INV), scaled if INV
template<int N, int LD, int NK, bool INV>
__device__ __forceinline__ void dft_cols(const float2* __restrict__ tmp,
                                         float2* __restrict__ io,
                                         const float2* __restrict__ tw, int tid) {
  constexpr int G = N / NK;
  if (tid < N * G) {
    const int k1g = tid / N, k2 = tid - N * k1g;
    float xr[NK], xi[NK], ar[NK], ai[NK];
#pragma unroll
    for (int j = 0; j < NK; ++j) {
      float2 w = tw[k1g * NK + j];
      xr[j] = w.x; xi[j] = INV ? -w.y : w.y;
    }
    const float2* col = tmp + k2;
    float2 v = col[(N - 1) * LD];
#pragma unroll
    for (int j = 0; j < NK; ++j) { ar[j] = v.x; ai[j] = v.y; }
#pragma unroll 2
    for (int r = N - 2; r >= 0; --r) {
      v = col[r * LD];
#pragma unroll
      for (int j = 0; j < NK; ++j) {
        float nr = fmaf(ar[j], xr[j], fmaf(-ai[j], xi[j], v.x));
        float ni = fmaf(ar[j], xi[j], fmaf(ai[j], xr[j], v.y));
        ar[j] = nr; ai[j] = ni;
      }
    }
    constexpr float scale = INV ? (1.f / (float)(N * N)) : 1.f;
#pragma unroll
    for (int j = 0; j < NK; ++j)
      io[(k1g * NK + j) * LD + k2] = make_float2(ar[j] * scale, ai[j] * scale);
  }
}

template<int N, int LD, int NK, bool INV>
__device__ void dft2d(float2* io, float2* tmp, const float2* tw, int tid) {
  __syncthreads();
  dft_rows<N, LD, NK, INV>(io, tmp, tw, tid);
  __syncthreads();
  dft_cols<N, LD, NK, INV>(tmp, io, tw, tid);
  __syncthreads();
}

// ---------- shared 20-path pipeline: fold2(A*ps) -> ifft20 -> |.| -> fft20 ->
//            fold2(phi1) -> ifft10 -> 8x8 unpad write ----------
__device__ void pipe20(const float2* __restrict__ A,   // 40x40 spectrum, LD 41
                       const float* __restrict__ ps,   // 40x40 filter, unpadded
                       const float* __restrict__ phi1, // 20x20 filter, unpadded
                       float2* C, float2* D, float2* P, float2* Q,
                       const float2* tw20, const float2* tw10,
                       float* __restrict__ outp, int tid) {
  for (int q = tid; q < 400; q += NTHR) {
    int q1 = q / 20, q2 = q - 20 * q1;
    float re = 0.f, im = 0.f;
#pragma unroll
    for (int a2 = 0; a2 < 2; ++a2)
#pragma unroll
      for (int b2 = 0; b2 < 2; ++b2) {
        int i40 = q1 + 20 * a2, j40 = q2 + 20 * b2;
        float ph = ps[i40 * 40 + j40];
        float2 v = A[i40 * 41 + j40];
        re = fmaf(v.x, ph, re); im = fmaf(v.y, ph, im);
      }
    C[q1 * 21 + q2] = make_float2(re * 0.25f, im * 0.25f);
  }
  dft2d<20, 21, 2, true>(C, D, tw20, tid);
  for (int o = tid; o < 400; o += NTHR) {
    int i = o / 20, j = o - 20 * i;
    float2 z = C[i * 21 + j];
    C[i * 21 + j] = make_float2(sqrtf(fmaf(z.x, z.x, z.y * z.y)), 0.f);
  }
  dft2d<20, 21, 2, false>(C, D, tw20, tid);
  for (int q = tid; q < 100; q += NTHR) {
    int q1 = q / 10, q2 = q - 10 * q1;
    float re = 0.f, im = 0.f;
#pragma unroll
    for (int a2 = 0; a2 < 2; ++a2)
#pragma unroll
      for (int b2 = 0; b2 < 2; ++b2) {
        int i20 = q1 + 10 * a2, j20 = q2 + 10 * b2;
        float ph = phi1[i20 * 20 + j20];
        float2 v = C[i20 * 21 + j20];
        re = fmaf(v.x, ph, re); im = fmaf(v.y, ph, im);
      }
    P[q1 * 11 + q2] = make_float2(re * 0.25f, im * 0.25f);
  }
  dft2d<10, 11, 1, true>(P, Q, tw10, tid);
  if (tid < 64) {
    int i = tid >> 3, j = tid & 7;
    outp[tid] = P[(i + 1) * 11 + (j + 1)].x;
  }
}

// ---------- Kernel 1: Morlet filter bank (double precision, on device) ----------
// filt layout (floats): phi0[1600] | phi1[400] | psi0[8*1600] | psi1[8*1600]
__device__ void dft2d40_f64(double2* io, double2* tmp, const double2* tw, int tid) {
  __syncthreads();
  for (int o = tid; o < 1600; o += NTHR) {
    int r = o / 40, k = o - 40 * r;
    double re = 0.0, im = 0.0;
    int idx = 0;
    for (int c = 0; c < 40; ++c) {
      double2 v = io[r * 40 + c];
      double2 w = tw[idx];
      re += v.x * w.x - v.y * w.y;
      im += v.x * w.y + v.y * w.x;
      idx += k; if (idx >= 40) idx -= 40;
    }
    tmp[o] = make_double2(re, im);
  }
  __syncthreads();
  for (int o = tid; o < 1600; o += NTHR) {
    int k1 = o / 40, k2 = o - 40 * k1;
    double re = 0.0, im = 0.0;
    int idx = 0;
    for (int r = 0; r < 40; ++r) {
      double2 v = tmp[r * 40 + k2];
      double2 w = tw[idx];
      re += v.x * w.x - v.y * w.y;
      im += v.x * w.y + v.y * w.x;
      idx += k1; if (idx >= 40) idx -= 40;
    }
    io[o] = make_double2(re, im);
  }
  __syncthreads();
}

__global__ __launch_bounds__(NTHR) void k_filters(float* __restrict__ filt) {
  const int fid = blockIdx.x;   // 0=phi, 1..8=psi0 t, 9..16=psi1 t
  const int tid = threadIdx.x;

  __shared__ double2 WV[1600];
  __shared__ float   EV[1600];
  __shared__ double2 TMP[1600];
  __shared__ double2 twd[40];
  __shared__ double  sred[3][4];
  __shared__ double  Kc[2];

  double sigma, theta, xi, slant; int morlet; int outOff;
  if (fid == 0)      { sigma = 3.2; theta = 0.0; xi = 0.0;                  slant = 1.0; morlet = 0; outOff = 0; }
  else if (fid <= 8) { int t = fid - 1; sigma = 0.8; theta = (3 - t) * M_PI / 8.0; xi = 3.0 * M_PI / 4.0; slant = 0.5; morlet = 1; outOff = 2000 + t * 1600; }
  else               { int t = fid - 9; sigma = 1.6; theta = (3 - t) * M_PI / 8.0; xi = 3.0 * M_PI / 8.0; slant = 0.5; morlet = 1; outOff = 14800 + t * 1600; }

  const double ct = cos(theta), st = sin(theta);
  const double sl2 = slant * slant;
  const double inv2s = 1.0 / (2.0 * sigma * sigma);
  const double ca = (ct * ct + sl2 * st * st) * inv2s;
  const double cb = (ct * st * (1.0 - sl2)) * inv2s;
  const double cd = (st * st + sl2 * ct * ct) * inv2s;
  const double norm = 2.0 * M_PI * sigma * sigma / slant;

  double swr = 0.0, swi = 0.0, ser = 0.0;
  for (int o = tid; o < 1600; o += NTHR) {
    int xr = o / 40, yc = o - 40 * xr;
    double wr = 0.0, wi = 0.0, er = 0.0;
    for (int ex = -2; ex <= 2; ++ex) {
      for (int ey = -2; ey <= 2; ++ey) {
        double xg = xr + ex * 40.0, yg = yc + ey * 40.0;
        double e = exp(-(ca * xg * xg + 2.0 * cb * xg * yg + cd * yg * yg));
        double ai = xi * (xg * ct + yg * st);
        double s, c;
        sincos(ai, &s, &c);
        wr += e * c; wi += e * s; er += e;
      }
    }
    wr /= norm; wi /= norm; er /= norm;
    WV[o] = make_double2(wr, wi);
    EV[o] = (float)er;
    swr += wr; swi += wi; ser += er;
  }
  for (int off = 32; off > 0; off >>= 1) {
    swr += __shfl_down(swr, off);
    swi += __shfl_down(swi, off);
    ser += __shfl_down(ser, off);
  }
  int lane = tid & 63, w = tid >> 6;
  if (lane == 0) { sred[0][w] = swr; sred[1][w] = swi; sred[2][w] = ser; }
  __syncthreads();
  if (tid == 0) {
    double A = 0, B = 0, C = 0;
    for (int i = 0; i < 4; ++i) { A += sred[0][i]; B += sred[1][i]; C += sred[2][i]; }
    Kc[0] = A / C; Kc[1] = B / C;
  }
  __syncthreads();
  if (morlet) {
    for (int o = tid; o < 1600; o += NTHR) {
      double e = (double)EV[o];
      WV[o].x -= Kc[0] * e;
      WV[o].y -= Kc[1] * e;
    }
  }
  for (int j = tid; j < 40; j += NTHR) {
    double s, c;
    sincos(-2.0 * M_PI * (double)j / 40.0, &s, &c);
    twd[j] = make_double2(c, s);
  }
  dft2d40_f64(WV, TMP, twd, tid);
  for (int o = tid; o < 1600; o += NTHR) filt[outOff + o] = (float)WV[o].x;
  if (fid == 0) {
    __syncthreads();
    for (int q = tid; q < 400; q += NTHR) {
      int q1 = q / 20, q2 = q - 20 * q1;
      double v = 0.25 * (WV[q1 * 40 + q2].x + WV[(q1 + 20) * 40 + q2].x +
                         WV[q1 * 40 + (q2 + 20)].x + WV[(q1 + 20) * 40 + (q2 + 20)].x);
      filt[1600 + q] = (float)v;
    }
  }
}

// ---------- Kernel 2: pad + fft2(xp) -> xf; S0 ----------
__global__ __launch_bounds__(NTHR) void k_fftx(const float* __restrict__ x,
                                               const float* __restrict__ filt,
                                               float2* __restrict__ xf_g,
                                               float* __restrict__ f) {
  const int bc = blockIdx.x;
  const int b = bc / 3, c = bc - 3 * b;
  const int tid = threadIdx.x;

  __shared__ float2 A[40 * 41], T[40 * 41];
  __shared__ float2 P[110], Q[110];
  __shared__ float2 tw40[40], tw10[10];

  init_tw(tw40, 40, tid);
  init_tw(tw10, 10, tid);

  const float* xb = x + (size_t)bc * 1024;
  for (int o = tid; o < 1600; o += NTHR) {
    int i = o / 40, j = o - 40 * i;
    int si = reflect32(i - 4), sj = reflect32(j - 4);
    A[i * 41 + j] = make_float2(xb[si * 32 + sj], 0.f);
  }
  dft2d<40, 41, 8, false>(A, T, tw40, tid);
  for (int o = tid; o < 1600; o += NTHR) {
    int i = o / 40, j = o - 40 * i;
    xf_g[(size_t)bc * 1600 + o] = A[i * 41 + j];
  }

  // S0 = ifft2_10( fold4( xf * phi0 ) ), real, [1:-1]
  const float* phi0 = filt;
  for (int q = tid; q < 100; q += NTHR) {
    int q1 = q / 10, q2 = q - 10 * q1;
    float re = 0.f, im = 0.f;
#pragma unroll
    for (int a2 = 0; a2 < 4; ++a2)
#pragma unroll
      for (int b2 = 0; b2 < 4; ++b2) {
        int i40 = q1 + 10 * a2, j40 = q2 + 10 * b2;
        float ph = phi0[i40 * 40 + j40];
        float2 v = A[i40 * 41 + j40];
        re = fmaf(v.x, ph, re); im = fmaf(v.y, ph, im);
      }
    P[q1 * 11 + q2] = make_float2(re * (1.f / 16.f), im * (1.f / 16.f));
  }
  dft2d<10, 11, 1, true>(P, Q, tw10, tid);
  float* fb = f + (size_t)b * 15552 + c * 5184;
  if (tid < 64) {
    int i = tid >> 3, j = tid & 7;
    fb[tid] = P[(i + 1) * 11 + (j + 1)].x;
  }
}

// ---------- Kernel 3: per (b,c,t): S1b, U1a, S1a, 8x S2 ----------
__global__ __launch_bounds__(NTHR) void k_main(const float2* __restrict__ xf_g,
                                               const float* __restrict__ filt,
                                               float* __restrict__ f) {
  const int blk = blockIdx.x;           // 384*8
  const int t = blk & 7;
  const int bc = blk >> 3;
  const int b = bc / 3, c = bc - 3 * b;
  const int tid = threadIdx.x;

  __shared__ float2 A[40 * 41];         // xf, then Ua_f
  __shared__ float2 T[40 * 41];         // DFT scratch
  __shared__ float2 C[420], D[420];     // 20x20 (LD 21)
  __shared__ float2 P[110], Q[110];     // 10x10 (LD 11)
  __shared__ float2 tw40[40], tw20[20], tw10[10];

  const float* phi0 = filt;
  const float* phi1 = filt + 1600;
  const float* psi0 = filt + 2000;
  const float* psi1 = filt + 14800;

  init_tw(tw40, 40, tid);
  init_tw(tw20, 20, tid);
  init_tw(tw10, 10, tid);

  const float2* xf = xf_g + (size_t)bc * 1600;
  for (int o = tid; o < 1600; o += NTHR) {
    int i = o / 40, j = o - 40 * i;
    A[i * 41 + j] = xf[o];
  }
  __syncthreads();

  float* fb = f + (size_t)b * 15552 + c * 5184;

  // S1b first (A still holds xf)
  pipe20(A, psi1 + t * 1600, phi1, C, D, P, Q, tw20, tw10, fb + (9 + t) * 64, tid);

  // A = xf * psi0[t]; Za = ifft2(A); U1a = |Za|; Ua_f = fft2(U1a)
  const float* ps0 = psi0 + t * 1600;
  for (int o = tid; o < 1600; o += NTHR) {
    int i = o / 40, j = o - 40 * i;
    float p = ps0[o];
    float2 v = A[i * 41 + j];
    A[i * 41 + j] = make_float2(v.x * p, v.y * p);
  }
  dft2d<40, 41, 8, true>(A, T, tw40, tid);
  for (int o = tid; o < 1600; o += NTHR) {
    int i = o / 40, j = o - 40 * i;
    float2 z = A[i * 41 + j];
    A[i * 41 + j] = make_float2(sqrtf(fmaf(z.x, z.x, z.y * z.y)), 0.f);
  }
  dft2d<40, 41, 8, false>(A, T, tw40, tid);

  // S1a = ifft2_10( fold4( Ua_f * phi0 ) )
  for (int q = tid; q < 100; q += NTHR) {
    int q1 = q / 10, q2 = q - 10 * q1;
    float re = 0.f, im = 0.f;
#pragma unroll
    for (int a2 = 0; a2 < 4; ++a2)
#pragma unroll
      for (int b2 = 0; b2 < 4; ++b2) {
        int i40 = q1 + 10 * a2, j40 = q2 + 10 * b2;
        float ph = phi0[i40 * 40 + j40];
        float2 v = A[i40 * 41 + j40];
        re = fmaf(v.x, ph, re); im = fmaf(v.y, ph, im);
      }
    P[q1 * 11 + q2] = make_float2(re * (1.f / 16.f), im * (1.f / 16.f));
  }
  dft2d<10, 11, 1, true>(P, Q, tw10, tid);
  if (tid < 64) {
    int i = tid >> 3, j = tid & 7;
    fb[(1 + t) * 64 + tid] = P[(i + 1) * 11 + (j + 1)].x;
  }

  // order 2
  for (int t2 = 0; t2 < 8; ++t2) {
    pipe20(A, psi1 + t2 * 1600, phi1, C, D, P, Q, tw20, tw10,
           fb + (17 + t * 8 + t2) * 64, tid);
  }
}

// ---------- Kernel 4: BN stats over batch ----------
__global__ __launch_bounds__(NTHR) void k_bn(const float* __restrict__ f,
                                             float* __restrict__ mu,
                                             float* __restrict__ rstd) {
  int col = blockIdx.x * NTHR + threadIdx.x;
  if (col >= 15552) return;
  double s = 0.0, s2 = 0.0;
  for (int b = 0; b < 128; ++b) {
    float v = f[(size_t)b * 15552 + col];
    s += v; s2 += (double)v * v;
  }
  double m = s / 128.0;
  double var = s2 / 128.0 - m * m;
  mu[col] = (float)m;
  rstd[col] = (float)(1.0 / sqrt(var + 1e-5));
}

// ---------- Kernel 5: normalize + relu ----------
__global__ __launch_bounds__(NTHR) void k_norm(const float* __restrict__ f,
                                               const float* __restrict__ mu,
                                               const float* __restrict__ rstd,
                                               const float* __restrict__ gamma,
                                               const float* __restrict__ beta,
                                               float* __restrict__ g) {
  size_t i = (size_t)blockIdx.x * NTHR + threadIdx.x;
  if (i >= (size_t)128 * 15552) return;
  int col = (int)(i % 15552);
  float v = (f[i] - mu[col]) * rstd[col] * gamma[col] + beta[col];
  g[i] = v > 0.f ? v : 0.f;
}

// ---------- Kernel 6: collapsed ToeplitzLike, first 10 outputs ----------
__global__ __launch_bounds__(NTHR) void k_out(const float* __restrict__ g,
                                              const float* __restrict__ Gm,
                                              const float* __restrict__ Hm,
                                              float* __restrict__ out) {
  const int b = blockIdx.x;
  const int tid = threadIdx.x;
  const float* gb = g + (size_t)b * 15552;

  float acc[40];
#pragma unroll
  for (int i = 0; i < 40; ++i) acc[i] = 0.f;

  for (int j = tid; j < 15552; j += NTHR) {
    float h[4];
#pragma unroll
    for (int r = 0; r < 4; ++r) h[r] = Hm[r * 15552 + j];
#pragma unroll
    for (int m = 0; m < 10; ++m) {
      int jm = j + m;
      float gv = (jm < 15552) ? gb[jm] : 0.f;
#pragma unroll
      for (int r = 0; r < 4; ++r) acc[r * 10 + m] += h[r] * gv;
    }
  }
#pragma unroll
  for (int i = 0; i < 40; ++i)
    for (int off = 32; off > 0; off >>= 1)
      acc[i] += __shfl_down(acc[i], off);

  __shared__ float red[4][40];
  __shared__ float Tm[40];
  int lane = tid & 63, w = tid >> 6;
  if (lane == 0) {
#pragma unroll
    for (int i = 0; i < 40; ++i) red[w][i] = acc[i];
  }
  __syncthreads();
  if (tid < 40) Tm[tid] = red[0][tid] + red[1][tid] + red[2][tid] + red[3][tid];
  __syncthreads();
  if (tid < 10) {
    float y = 0.f;
    for (int r = 0; r < 4; ++r)
      for (int m = 0; m <= tid; ++m)
        y += Gm[r * 15552 + (tid - m)] * Tm[r * 10 + m];
    out[b * 10 + tid] = y;
  }
}

extern "C" void kernel_launch(void* const* d_in, const int* in_sizes, int n_in,
                              void* d_out, int out_size, void* d_ws, size_t ws_size,
                              hipStream_t stream) {
  (void)in_sizes; (void)n_in; (void)out_size; (void)ws_size;
  const float* x     = (const float*)d_in[0];   // (128,3,32,32)
  const float* gamma = (const float*)d_in[1];   // (15552,)
  const float* beta  = (const float*)d_in[2];   // (15552,)
  const float* G     = (const float*)d_in[3];   // (4,15552)
  const float* H     = (const float*)d_in[4];   // (4,15552)
  float* out = (float*)d_out;                   // (128,10)

  float* ws   = (float*)d_ws;
  float* filt = ws;                         // 27600
  float* xf   = filt + 27600;               // 384*1600*2 = 1228800
  float* f    = xf + 1228800;               // 128*15552 = 1990656
  float* g    = f + 1990656;                // 1990656
  float* mu   = g + 1990656;                // 15552
  float* rstd = mu + 15552;                 // 15552

  k_filters<<<17, NTHR, 0, stream>>>(filt);
  k_fftx<<<384, NTHR, 0, stream>>>(x, filt, (float2*)xf, f);
  k_main<<<3072, NTHR, 0, stream>>>((const float2*)xf, filt, f);
  k_bn<<<61, NTHR, 0, stream>>>(f, mu, rstd);
  k_norm<<<7776, NTHR, 0, stream>>>(f, mu, rstd, gamma, beta, g);
  k_out<<<128, NTHR, 0, stream>>>(g, G, H, out);
}

// Round 5
// 393.338 us; speedup vs baseline: 2.2142x; 1.2517x over previous
//
#include <hip/hip_runtime.h>
#include <math.h>

#define NTHR 256

__device__ __forceinline__ int reflect32(int v) {
  if (v < 0) v = -v;
  if (v > 31) v = 62 - v;
  return v;
}

__device__ __forceinline__ void init_tw(float2* tw, int N, int tid) {
  for (int j = tid; j < N; j += NTHR) {
    float s, c;
    sincosf(-2.0f * (float)M_PI * (float)j / (float)N, &s, &c);
    tw[j] = make_float2(c, s);
  }
}

// ---------- Horner DFT passes (batched) ----------
// rows: tmp[a][r][k] = sum_c io[a][r][c] * x^c, x = tw[k] (conj if INV)
template<int N, int LD, int NK, bool INV, int B, int AS>
__device__ __forceinline__ void dftB_rows(const float2* __restrict__ io,
                                          float2* __restrict__ tmp,
                                          const float2* __restrict__ tw, int tid) {
  constexpr int G = N / NK;
  constexpr int UNITS = B * N * G;
  for (int u = tid; u < UNITS; u += NTHR) {
    const int a = u / (N * G);
    const int rem = u - a * (N * G);
    const int r = rem / G, kg = rem - G * r;
    float xr[NK], xi[NK], ar[NK], ai[NK];
#pragma unroll
    for (int j = 0; j < NK; ++j) {
      float2 w = tw[kg * NK + j];
      xr[j] = w.x; xi[j] = INV ? -w.y : w.y;
    }
    const float2* row = io + a * AS + r * LD;
    float2 v = row[N - 1];
#pragma unroll
    for (int j = 0; j < NK; ++j) { ar[j] = v.x; ai[j] = v.y; }
#pragma unroll 2
    for (int cc = N - 2; cc >= 0; --cc) {
      v = row[cc];
#pragma unroll
      for (int j = 0; j < NK; ++j) {
        float nr = fmaf(ar[j], xr[j], fmaf(-ai[j], xi[j], v.x));
        float ni = fmaf(ar[j], xi[j], fmaf(ai[j], xr[j], v.y));
        ar[j] = nr; ai[j] = ni;
      }
    }
    float2* orow = tmp + a * AS + r * LD + kg * NK;
#pragma unroll
    for (int j = 0; j < NK; ++j) orow[j] = make_float2(ar[j], ai[j]);
  }
}

// cols: io[a][k1][k2] = sum_r tmp[a][r][k2] * x^r, x = tw[k1] (conj+scale if INV)
template<int N, int LD, int NK, bool INV, int B, int AS>
__device__ __forceinline__ void dftB_cols(const float2* __restrict__ tmp,
                                          float2* __restrict__ io,
                                          const float2* __restrict__ tw, int tid) {
  constexpr int G = N / NK;
  constexpr int UNITS = B * N * G;
  for (int u = tid; u < UNITS; u += NTHR) {
    const int a = u / (N * G);
    const int rem = u - a * (N * G);
    const int k1g = rem / N, k2 = rem - N * k1g;
    float xr[NK], xi[NK], ar[NK], ai[NK];
#pragma unroll
    for (int j = 0; j < NK; ++j) {
      float2 w = tw[k1g * NK + j];
      xr[j] = w.x; xi[j] = INV ? -w.y : w.y;
    }
    const float2* col = tmp + a * AS + k2;
    float2 v = col[(N - 1) * LD];
#pragma unroll
    for (int j = 0; j < NK; ++j) { ar[j] = v.x; ai[j] = v.y; }
#pragma unroll 2
    for (int r = N - 2; r >= 0; --r) {
      v = col[r * LD];
#pragma unroll
      for (int j = 0; j < NK; ++j) {
        float nr = fmaf(ar[j], xr[j], fmaf(-ai[j], xi[j], v.x));
        float ni = fmaf(ar[j], xi[j], fmaf(ai[j], xr[j], v.y));
        ar[j] = nr; ai[j] = ni;
      }
    }
    constexpr float scale = INV ? (1.f / (float)(N * N)) : 1.f;
#pragma unroll
    for (int j = 0; j < NK; ++j)
      io[a * AS + (k1g * NK + j) * LD + k2] = make_float2(ar[j] * scale, ai[j] * scale);
  }
}

// caller must __syncthreads() after filling io, before calling
template<int N, int LD, int NK, bool INV, int B, int AS>
__device__ __forceinline__ void dft2dB(float2* io, float2* tmp, const float2* tw, int tid) {
  dftB_rows<N, LD, NK, INV, B, AS>(io, tmp, tw, tid);
  __syncthreads();
  dftB_cols<N, LD, NK, INV, B, AS>(tmp, io, tw, tid);
  __syncthreads();
}

// ---------- rfft40: forward FFT of real 40x40 (LD 41), half spectrum ----------
// rows pass, real input (.x), k = 0..KH-1
template<int NK, int KH>
__device__ __forceinline__ void rdft40_rows(const float2* __restrict__ io,
                                            float2* __restrict__ tmp,
                                            const float2* __restrict__ tw, int tid) {
  constexpr int G = KH / NK;      // 24/4 = 6
  constexpr int UNITS = 40 * G;   // 240
  if (tid < UNITS) {
    const int r = tid / G, kg = tid - G * r;
    float xr[NK], xi[NK], ar[NK], ai[NK];
#pragma unroll
    for (int j = 0; j < NK; ++j) { float2 w = tw[kg * NK + j]; xr[j] = w.x; xi[j] = w.y; }
    const float2* row = io + r * 41;
    float v = row[39].x;
#pragma unroll
    for (int j = 0; j < NK; ++j) { ar[j] = v; ai[j] = 0.f; }
#pragma unroll 2
    for (int cc = 38; cc >= 0; --cc) {
      v = row[cc].x;
#pragma unroll
      for (int j = 0; j < NK; ++j) {
        float nr = fmaf(ar[j], xr[j], fmaf(-ai[j], xi[j], v));
        float ni = fmaf(ar[j], xi[j], ai[j] * xr[j]);
        ar[j] = nr; ai[j] = ni;
      }
    }
    float2* orow = tmp + r * 41 + kg * NK;
#pragma unroll
    for (int j = 0; j < NK; ++j) orow[j] = make_float2(ar[j], ai[j]);
  }
}

// cols pass over KH columns, all 40 k1, forward
template<int NK, int KH>
__device__ __forceinline__ void dft40_colsK(const float2* __restrict__ tmp,
                                            float2* __restrict__ io,
                                            const float2* __restrict__ tw, int tid) {
  constexpr int G = 40 / NK;      // 10
  constexpr int UNITS = KH * G;   // 240
  if (tid < UNITS) {
    const int k1g = tid / KH, k2 = tid - KH * k1g;
    float xr[NK], xi[NK], ar[NK], ai[NK];
#pragma unroll
    for (int j = 0; j < NK; ++j) { float2 w = tw[k1g * NK + j]; xr[j] = w.x; xi[j] = w.y; }
    const float2* col = tmp + k2;
    float2 v = col[39 * 41];
#pragma unroll
    for (int j = 0; j < NK; ++j) { ar[j] = v.x; ai[j] = v.y; }
#pragma unroll 2
    for (int r = 38; r >= 0; --r) {
      v = col[r * 41];
#pragma unroll
      for (int j = 0; j < NK; ++j) {
        float nr = fmaf(ar[j], xr[j], fmaf(-ai[j], xi[j], v.x));
        float ni = fmaf(ar[j], xi[j], fmaf(ai[j], xr[j], v.y));
        ar[j] = nr; ai[j] = ni;
      }
    }
#pragma unroll
    for (int j = 0; j < NK; ++j)
      io[(k1g * NK + j) * 41 + k2] = make_float2(ar[j], ai[j]);
  }
}

// Hermitian mirror fill: A[k1][k2] = conj(A[(40-k1)%40][40-k2]) for k2 = 21..39
__device__ __forceinline__ void mirror40(float2* __restrict__ A, int tid) {
  for (int o = tid; o < 760; o += NTHR) {
    int d = o / 40;
    int k2 = 21 + d, k1 = o - 40 * d;
    float2 v = A[((40 - k1) % 40) * 41 + (40 - k2)];
    A[k1 * 41 + k2] = make_float2(v.x, -v.y);
  }
}

// ---------- Kernel 1: Morlet filter bank (f32, on device) ----------
// filt layout (floats): phi0[1600] | phi1[400] | psi0[8*1600] | psi1[8*1600]
__global__ __launch_bounds__(NTHR) void k_filters(float* __restrict__ filt) {
  const int fid = blockIdx.x;   // 0=phi, 1..8=psi0 t, 9..16=psi1 t
  const int tid = threadIdx.x;

  __shared__ float2 WV[40 * 41];
  __shared__ float  EV[1600];
  __shared__ float2 T[40 * 41];
  __shared__ float2 tw40[40];
  __shared__ float  sred[3][4];
  __shared__ float  Kc[2];

  double sigma, theta, xi, slant; int morlet; int outOff;
  if (fid == 0)      { sigma = 3.2; theta = 0.0; xi = 0.0;                  slant = 1.0; morlet = 0; outOff = 0; }
  else if (fid <= 8) { int t = fid - 1; sigma = 0.8; theta = (3 - t) * M_PI / 8.0; xi = 3.0 * M_PI / 4.0; slant = 0.5; morlet = 1; outOff = 2000 + t * 1600; }
  else               { int t = fid - 9; sigma = 1.6; theta = (3 - t) * M_PI / 8.0; xi = 3.0 * M_PI / 8.0; slant = 0.5; morlet = 1; outOff = 14800 + t * 1600; }

  const double ctd = cos(theta), std_ = sin(theta);
  const double sl2 = slant * slant;
  const double inv2s = 1.0 / (2.0 * sigma * sigma);
  const float ca = (float)((ctd * ctd + sl2 * std_ * std_) * inv2s);
  const float cb = (float)((ctd * std_ * (1.0 - sl2)) * inv2s);
  const float cd = (float)((std_ * std_ + sl2 * ctd * ctd) * inv2s);
  const float rnorm = (float)(slant / (2.0 * M_PI * sigma * sigma));
  const float ct = (float)ctd, st = (float)std_;
  const float xif = (float)xi;

  float swr = 0.f, swi = 0.f, ser = 0.f;
  for (int o = tid; o < 1600; o += NTHR) {
    int xr = o / 40, yc = o - 40 * xr;
    float wr = 0.f, wi = 0.f, er = 0.f;
    for (int ex = -2; ex <= 2; ++ex) {
      for (int ey = -2; ey <= 2; ++ey) {
        float xg = (float)xr + ex * 40.f, yg = (float)yc + ey * 40.f;
        float e = expf(-(ca * xg * xg + 2.f * cb * xg * yg + cd * yg * yg));
        float ang = xif * (xg * ct + yg * st);
        float s, c;
        sincosf(ang, &s, &c);
        wr = fmaf(e, c, wr); wi = fmaf(e, s, wi); er += e;
      }
    }
    wr *= rnorm; wi *= rnorm; er *= rnorm;
    WV[xr * 41 + yc] = make_float2(wr, wi);
    EV[o] = er;
    swr += wr; swi += wi; ser += er;
  }
  for (int off = 32; off > 0; off >>= 1) {
    swr += __shfl_down(swr, off);
    swi += __shfl_down(swi, off);
    ser += __shfl_down(ser, off);
  }
  int lane = tid & 63, w = tid >> 6;
  if (lane == 0) { sred[0][w] = swr; sred[1][w] = swi; sred[2][w] = ser; }
  __syncthreads();
  if (tid == 0) {
    float A = 0, B = 0, C = 0;
    for (int i = 0; i < 4; ++i) { A += sred[0][i]; B += sred[1][i]; C += sred[2][i]; }
    Kc[0] = A / C; Kc[1] = B / C;
  }
  init_tw(tw40, 40, tid);
  __syncthreads();
  if (morlet) {
    for (int o = tid; o < 1600; o += NTHR) {
      int i = o / 40, j = o - 40 * i;
      float e = EV[o];
      WV[i * 41 + j].x -= Kc[0] * e;
      WV[i * 41 + j].y -= Kc[1] * e;
    }
  }
  __syncthreads();
  dft2dB<40, 41, 8, false, 1, 0>(WV, T, tw40, tid);
  for (int o = tid; o < 1600; o += NTHR) {
    int i = o / 40, j = o - 40 * i;
    filt[outOff + o] = WV[i * 41 + j].x;
  }
  if (fid == 0) {
    // phi1 = periodize(phi0, 1): 2x2 spectral fold (mean)
    for (int q = tid; q < 400; q += NTHR) {
      int q1 = q / 20, q2 = q - 20 * q1;
      float v = 0.25f * (WV[q1 * 41 + q2].x + WV[(q1 + 20) * 41 + q2].x +
                         WV[q1 * 41 + (q2 + 20)].x + WV[(q1 + 20) * 41 + (q2 + 20)].x);
      filt[1600 + q] = v;
    }
  }
}

// ---------- Kernel 2: pad + rfft40(xp) -> xf; S0 ----------
__global__ __launch_bounds__(NTHR) void k_fftx(const float* __restrict__ x,
                                               const float* __restrict__ filt,
                                               float2* __restrict__ xf_g,
                                               float* __restrict__ f) {
  const int bc = blockIdx.x;
  const int b = bc / 3, c = bc - 3 * b;
  const int tid = threadIdx.x;

  __shared__ float2 A[40 * 41], T[40 * 41];
  __shared__ float2 P[110], Q[110];
  __shared__ float2 tw40[40], tw10[10];

  init_tw(tw40, 40, tid);
  init_tw(tw10, 10, tid);

  const float* xb = x + (size_t)bc * 1024;
  for (int o = tid; o < 1600; o += NTHR) {
    int i = o / 40, j = o - 40 * i;
    int si = reflect32(i - 4), sj = reflect32(j - 4);
    A[i * 41 + j] = make_float2(xb[si * 32 + sj], 0.f);
  }
  __syncthreads();
  rdft40_rows<4, 24>(A, T, tw40, tid);
  __syncthreads();
  dft40_colsK<4, 24>(T, A, tw40, tid);
  __syncthreads();
  mirror40(A, tid);
  __syncthreads();
  for (int o = tid; o < 1600; o += NTHR) {
    int i = o / 40, j = o - 40 * i;
    xf_g[(size_t)bc * 1600 + o] = A[i * 41 + j];
  }

  // S0 = ifft2_10( fold4( xf * phi0 ) ), real, [1:-1]
  const float* phi0 = filt;
  for (int q = tid; q < 100; q += NTHR) {
    int q1 = q / 10, q2 = q - 10 * q1;
    float re = 0.f, im = 0.f;
#pragma unroll
    for (int a2 = 0; a2 < 4; ++a2)
#pragma unroll
      for (int b2 = 0; b2 < 4; ++b2) {
        int i40 = q1 + 10 * a2, j40 = q2 + 10 * b2;
        float ph = phi0[i40 * 40 + j40];
        float2 v = A[i40 * 41 + j40];
        re = fmaf(v.x, ph, re); im = fmaf(v.y, ph, im);
      }
    P[q1 * 11 + q2] = make_float2(re * (1.f / 16.f), im * (1.f / 16.f));
  }
  __syncthreads();
  dft2dB<10, 11, 1, true, 1, 0>(P, Q, tw10, tid);
  float* fb = f + (size_t)b * 15552 + c * 5184;
  if (tid < 64) {
    int i = tid >> 3, j = tid & 7;
    fb[tid] = P[(i + 1) * 11 + (j + 1)].x;
  }
}

// ---------- Kernel 3: per (b,c,t): S1b, U1a, S1a, 4 paired S2 ----------
__global__ __launch_bounds__(NTHR) void k_main(const float2* __restrict__ xf_g,
                                               const float* __restrict__ filt,
                                               float* __restrict__ f) {
  const int blk = blockIdx.x;           // 384*8
  const int t = blk & 7;
  const int bc = blk >> 3;
  const int b = bc / 3, c = bc - 3 * b;
  const int tid = threadIdx.x;

  __shared__ float2 A[40 * 41];         // xf, then Ua_f
  __shared__ float2 T[40 * 41];         // DFT scratch
  __shared__ float2 C[2 * 420];         // 2x 20x20 (LD 21)
  __shared__ float2 P[110], Q[110];     // 10x10 (LD 11)
  __shared__ float2 tw40[40], tw20[20], tw10[10];

  const float* phi0 = filt;
  const float* phi1 = filt + 1600;
  const float* psi0 = filt + 2000;
  const float* psi1 = filt + 14800;

  init_tw(tw40, 40, tid);
  init_tw(tw20, 20, tid);
  init_tw(tw10, 10, tid);

  const float2* xf = xf_g + (size_t)bc * 1600;
  for (int o = tid; o < 1600; o += NTHR) {
    int i = o / 40, j = o - 40 * i;
    A[i * 41 + j] = xf[o];
  }
  __syncthreads();

  float* fb = f + (size_t)b * 15552 + c * 5184;

  // ---- S1b: fold2(xf*psi1[t]) -> ifft20 -> |.| -> fft20 -> fold2(phi1) -> Q
  const float* ps1t = psi1 + t * 1600;
  for (int q = tid; q < 400; q += NTHR) {
    int q1 = q / 20, q2 = q - 20 * q1;
    float re = 0.f, im = 0.f;
#pragma unroll
    for (int a2 = 0; a2 < 2; ++a2)
#pragma unroll
      for (int b2 = 0; b2 < 2; ++b2) {
        int i40 = q1 + 20 * a2, j40 = q2 + 20 * b2;
        float ph = ps1t[i40 * 40 + j40];
        float2 v = A[i40 * 41 + j40];
        re = fmaf(v.x, ph, re); im = fmaf(v.y, ph, im);
      }
    C[q1 * 21 + q2] = make_float2(re * 0.25f, im * 0.25f);
  }
  __syncthreads();
  dft2dB<20, 21, 2, true, 1, 420>(C, T, tw20, tid);
  for (int o = tid; o < 400; o += NTHR) {
    int i = o / 20, j = o - 20 * i;
    float2 z = C[i * 21 + j];
    C[i * 21 + j] = make_float2(sqrtf(fmaf(z.x, z.x, z.y * z.y)), 0.f);
  }
  __syncthreads();
  dft2dB<20, 21, 2, false, 1, 420>(C, T, tw20, tid);
  for (int q = tid; q < 100; q += NTHR) {
    int q1 = q / 10, q2 = q - 10 * q1;
    float re = 0.f, im = 0.f;
#pragma unroll
    for (int a2 = 0; a2 < 2; ++a2)
#pragma unroll
      for (int b2 = 0; b2 < 2; ++b2) {
        int i20 = q1 + 10 * a2, j20 = q2 + 10 * b2;
        float ph = phi1[i20 * 20 + j20];
        float2 v = C[i20 * 21 + j20];
        re = fmaf(v.x, ph, re); im = fmaf(v.y, ph, im);
      }
    Q[q1 * 11 + q2] = make_float2(re * 0.25f, im * 0.25f);
  }

  // ---- 40-pt path: A = xf*psi0[t]; ifft40; |.|; rfft40 -> Ua_f (Hermitian)
  const float* ps0 = psi0 + t * 1600;
  for (int o = tid; o < 1600; o += NTHR) {
    int i = o / 40, j = o - 40 * i;
    float p = ps0[o];
    float2 v = A[i * 41 + j];
    A[i * 41 + j] = make_float2(v.x * p, v.y * p);
  }
  __syncthreads();
  dft2dB<40, 41, 8, true, 1, 0>(A, T, tw40, tid);
  for (int o = tid; o < 1600; o += NTHR) {
    int i = o / 40, j = o - 40 * i;
    float2 z = A[i * 41 + j];
    A[i * 41 + j] = make_float2(sqrtf(fmaf(z.x, z.x, z.y * z.y)), 0.f);
  }
  __syncthreads();
  rdft40_rows<4, 24>(A, T, tw40, tid);
  __syncthreads();
  dft40_colsK<4, 24>(T, A, tw40, tid);
  __syncthreads();
  mirror40(A, tid);
  __syncthreads();

  // ---- S1a fold4 -> P, pack with Q (both Hermitian -> one ifft10)
  for (int q = tid; q < 100; q += NTHR) {
    int q1 = q / 10, q2 = q - 10 * q1;
    float re = 0.f, im = 0.f;
#pragma unroll
    for (int a2 = 0; a2 < 4; ++a2)
#pragma unroll
      for (int b2 = 0; b2 < 4; ++b2) {
        int i40 = q1 + 10 * a2, j40 = q2 + 10 * b2;
        float ph = phi0[i40 * 40 + j40];
        float2 v = A[i40 * 41 + j40];
        re = fmaf(v.x, ph, re); im = fmaf(v.y, ph, im);
      }
    float2 qb = Q[q1 * 11 + q2];
    P[q1 * 11 + q2] = make_float2(re * (1.f / 16.f) - qb.y, im * (1.f / 16.f) + qb.x);
  }
  __syncthreads();
  dft2dB<10, 11, 1, true, 1, 0>(P, C, tw10, tid);
  if (tid < 64) {
    int i = tid >> 3, j = tid & 7;
    float2 v = P[(i + 1) * 11 + (j + 1)];
    fb[(1 + t) * 64 + tid] = v.x;   // S1a
    fb[(9 + t) * 64 + tid] = v.y;   // S1b
  }

  // ---- order 2: pairs (2p, 2p+1); pack real U2 pair into one complex fft20
  for (int p = 0; p < 4; ++p) {
    const float* pa = psi1 + (2 * p) * 1600;
    const float* pb = psi1 + (2 * p + 1) * 1600;
    __syncthreads();
    for (int q = tid; q < 800; q += NTHR) {
      int a = (q >= 400) ? 1 : 0;
      int qq = q - 400 * a;
      const float* ps = a ? pb : pa;
      int q1 = qq / 20, q2 = qq - 20 * q1;
      float re = 0.f, im = 0.f;
#pragma unroll
      for (int a2 = 0; a2 < 2; ++a2)
#pragma unroll
        for (int b2 = 0; b2 < 2; ++b2) {
          int i40 = q1 + 20 * a2, j40 = q2 + 20 * b2;
          float ph = ps[i40 * 40 + j40];
          float2 v = A[i40 * 41 + j40];
          re = fmaf(v.x, ph, re); im = fmaf(v.y, ph, im);
        }
      C[a * 420 + q1 * 21 + q2] = make_float2(re * 0.25f, im * 0.25f);
    }
    __syncthreads();
    dft2dB<20, 21, 2, true, 2, 420>(C, T, tw20, tid);
    // pack magnitudes: C0 = |U2a| + i*|U2b|
    for (int o = tid; o < 400; o += NTHR) {
      int i = o / 20, j = o - 20 * i;
      int idx = i * 21 + j;
      float2 z0 = C[idx], z1 = C[420 + idx];
      C[idx] = make_float2(sqrtf(fmaf(z0.x, z0.x, z0.y * z0.y)),
                           sqrtf(fmaf(z1.x, z1.x, z1.y * z1.y)));
    }
    __syncthreads();
    dft2dB<20, 21, 2, false, 1, 420>(C, T, tw20, tid);
    for (int q = tid; q < 100; q += NTHR) {
      int q1 = q / 10, q2 = q - 10 * q1;
      float re = 0.f, im = 0.f;
#pragma unroll
      for (int a2 = 0; a2 < 2; ++a2)
#pragma unroll
        for (int b2 = 0; b2 < 2; ++b2) {
          int i20 = q1 + 10 * a2, j20 = q2 + 10 * b2;
          float ph = phi1[i20 * 20 + j20];
          float2 v = C[i20 * 21 + j20];
          re = fmaf(v.x, ph, re); im = fmaf(v.y, ph, im);
        }
      P[q1 * 11 + q2] = make_float2(re * 0.25f, im * 0.25f);
    }
    __syncthreads();
    dft2dB<10, 11, 1, true, 1, 0>(P, C + 420, tw10, tid);
    if (tid < 64) {
      int i = tid >> 3, j = tid & 7;
      float2 v = P[(i + 1) * 11 + (j + 1)];
      fb[(17 + t * 8 + 2 * p) * 64 + tid] = v.x;
      fb[(17 + t * 8 + 2 * p + 1) * 64 + tid] = v.y;
    }
  }
}

// ---------- Kernel 4: BN stats over batch ----------
__global__ __launch_bounds__(NTHR) void k_bn(const float* __restrict__ f,
                                             float* __restrict__ mu,
                                             float* __restrict__ rstd) {
  int col = blockIdx.x * NTHR + threadIdx.x;
  if (col >= 15552) return;
  double s = 0.0, s2 = 0.0;
  for (int b = 0; b < 128; ++b) {
    float v = f[(size_t)b * 15552 + col];
    s += v; s2 += (double)v * v;
  }
  double m = s / 128.0;
  double var = s2 / 128.0 - m * m;
  mu[col] = (float)m;
  rstd[col] = (float)(1.0 / sqrt(var + 1e-5));
}

// ---------- Kernel 5: normalize + relu ----------
__global__ __launch_bounds__(NTHR) void k_norm(const float* __restrict__ f,
                                               const float* __restrict__ mu,
                                               const float* __restrict__ rstd,
                                               const float* __restrict__ gamma,
                                               const float* __restrict__ beta,
                                               float* __restrict__ g) {
  size_t i = (size_t)blockIdx.x * NTHR + threadIdx.x;
  if (i >= (size_t)128 * 15552) return;
  int col = (int)(i % 15552);
  float v = (f[i] - mu[col]) * rstd[col] * gamma[col] + beta[col];
  g[i] = v > 0.f ? v : 0.f;
}

// ---------- Kernel 6: collapsed ToeplitzLike, first 10 outputs ----------
__global__ __launch_bounds__(NTHR) void k_out(const float* __restrict__ g,
                                              const float* __restrict__ Gm,
                                              const float* __restrict__ Hm,
                                              float* __restrict__ out) {
  const int b = blockIdx.x;
  const int tid = threadIdx.x;
  const float* gb = g + (size_t)b * 15552;

  float acc[40];
#pragma unroll
  for (int i = 0; i < 40; ++i) acc[i] = 0.f;

  for (int j = tid; j < 15552; j += NTHR) {
    float h[4];
#pragma unroll
    for (int r = 0; r < 4; ++r) h[r] = Hm[r * 15552 + j];
#pragma unroll
    for (int m = 0; m < 10; ++m) {
      int jm = j + m;
      float gv = (jm < 15552) ? gb[jm] : 0.f;
#pragma unroll
      for (int r = 0; r < 4; ++r) acc[r * 10 + m] += h[r] * gv;
    }
  }
#pragma unroll
  for (int i = 0; i < 40; ++i)
    for (int off = 32; off > 0; off >>= 1)
      acc[i] += __shfl_down(acc[i], off);

  __shared__ float red[4][40];
  __shared__ float Tm[40];
  int lane = tid & 63, w = tid >> 6;
  if (lane == 0) {
#pragma unroll
    for (int i = 0; i < 40; ++i) red[w][i] = acc[i];
  }
  __syncthreads();
  if (tid < 40) Tm[tid] = red[0][tid] + red[1][tid] + red[2][tid] + red[3][tid];
  __syncthreads();
  if (tid < 10) {
    float y = 0.f;
    for (int r = 0; r < 4; ++r)
      for (int m = 0; m <= tid; ++m)
        y += Gm[r * 15552 + (tid - m)] * Tm[r * 10 + m];
    out[b * 10 + tid] = y;
  }
}

extern "C" void kernel_launch(void* const* d_in, const int* in_sizes, int n_in,
                              void* d_out, int out_size, void* d_ws, size_t ws_size,
                              hipStream_t stream) {
  (void)in_sizes; (void)n_in; (void)out_size; (void)ws_size;
  const float* x     = (const float*)d_in[0];   // (128,3,32,32)
  const float* gamma = (const float*)d_in[1];   // (15552,)
  const float* beta  = (const float*)d_in[2];   // (15552,)
  const float* G     = (const float*)d_in[3];   // (4,15552)
  const float* H     = (const float*)d_in[4];   // (4,15552)
  float* out = (float*)d_out;                   // (128,10)

  float* ws   = (float*)d_ws;
  float* filt = ws;                         // 27600
  float* xf   = filt + 27600;               // 384*1600*2 = 1228800
  float* f    = xf + 1228800;               // 128*15552 = 1990656
  float* g    = f + 1990656;                // 1990656
  float* mu   = g + 1990656;                // 15552
  float* rstd = mu + 15552;                 // 15552

  k_filters<<<17, NTHR, 0, stream>>>(filt);
  k_fftx<<<384, NTHR, 0, stream>>>(x, filt, (float2*)xf, f);
  k_main<<<3072, NTHR, 0, stream>>>((const float2*)xf, filt, f);
  k_bn<<<61, NTHR, 0, stream>>>(f, mu, rstd);
  k_norm<<<7776, NTHR, 0, stream>>>(f, mu, rstd, gamma, beta, g);
  k_out<<<128, NTHR, 0, stream>>>(g, G, H, out);
}

// Round 6
// 382.117 us; speedup vs baseline: 2.2792x; 1.0294x over previous
//
#include <hip/hip_runtime.h>
#include <math.h>

#define NTHR 256

__device__ __forceinline__ int reflect32(int v) {
  if (v < 0) v = -v;
  if (v > 31) v = 62 - v;
  return v;
}

__device__ __forceinline__ void init_tw(float2* tw, int N, int tid) {
  for (int j = tid; j < N; j += NTHR) {
    float s, c;
    sincosf(-2.0f * (float)M_PI * (float)j / (float)N, &s, &c);
    tw[j] = make_float2(c, s);
  }
}

// ---------- Horner DFT passes (batched) — kept for 20-pt / 10-pt / filters ----------
template<int N, int LD, int NK, bool INV, int B, int AS>
__device__ __forceinline__ void dftB_rows(const float2* __restrict__ io,
                                          float2* __restrict__ tmp,
                                          const float2* __restrict__ tw, int tid) {
  constexpr int G = N / NK;
  constexpr int UNITS = B * N * G;
  for (int u = tid; u < UNITS; u += NTHR) {
    const int a = u / (N * G);
    const int rem = u - a * (N * G);
    const int r = rem / G, kg = rem - G * r;
    float xr[NK], xi[NK], ar[NK], ai[NK];
#pragma unroll
    for (int j = 0; j < NK; ++j) {
      float2 w = tw[kg * NK + j];
      xr[j] = w.x; xi[j] = INV ? -w.y : w.y;
    }
    const float2* row = io + a * AS + r * LD;
    float2 v = row[N - 1];
#pragma unroll
    for (int j = 0; j < NK; ++j) { ar[j] = v.x; ai[j] = v.y; }
#pragma unroll 2
    for (int cc = N - 2; cc >= 0; --cc) {
      v = row[cc];
#pragma unroll
      for (int j = 0; j < NK; ++j) {
        float nr = fmaf(ar[j], xr[j], fmaf(-ai[j], xi[j], v.x));
        float ni = fmaf(ar[j], xi[j], fmaf(ai[j], xr[j], v.y));
        ar[j] = nr; ai[j] = ni;
      }
    }
    float2* orow = tmp + a * AS + r * LD + kg * NK;
#pragma unroll
    for (int j = 0; j < NK; ++j) orow[j] = make_float2(ar[j], ai[j]);
  }
}

template<int N, int LD, int NK, bool INV, int B, int AS>
__device__ __forceinline__ void dftB_cols(const float2* __restrict__ tmp,
                                          float2* __restrict__ io,
                                          const float2* __restrict__ tw, int tid) {
  constexpr int G = N / NK;
  constexpr int UNITS = B * N * G;
  for (int u = tid; u < UNITS; u += NTHR) {
    const int a = u / (N * G);
    const int rem = u - a * (N * G);
    const int k1g = rem / N, k2 = rem - N * k1g;
    float xr[NK], xi[NK], ar[NK], ai[NK];
#pragma unroll
    for (int j = 0; j < NK; ++j) {
      float2 w = tw[k1g * NK + j];
      xr[j] = w.x; xi[j] = INV ? -w.y : w.y;
    }
    const float2* col = tmp + a * AS + k2;
    float2 v = col[(N - 1) * LD];
#pragma unroll
    for (int j = 0; j < NK; ++j) { ar[j] = v.x; ai[j] = v.y; }
#pragma unroll 2
    for (int r = N - 2; r >= 0; --r) {
      v = col[r * LD];
#pragma unroll
      for (int j = 0; j < NK; ++j) {
        float nr = fmaf(ar[j], xr[j], fmaf(-ai[j], xi[j], v.x));
        float ni = fmaf(ar[j], xi[j], fmaf(ai[j], xr[j], v.y));
        ar[j] = nr; ai[j] = ni;
      }
    }
    constexpr float scale = INV ? (1.f / (float)(N * N)) : 1.f;
#pragma unroll
    for (int j = 0; j < NK; ++j)
      io[a * AS + (k1g * NK + j) * LD + k2] = make_float2(ar[j] * scale, ai[j] * scale);
  }
}

// caller must __syncthreads() after filling io, before calling
template<int N, int LD, int NK, bool INV, int B, int AS>
__device__ __forceinline__ void dft2dB(float2* io, float2* tmp, const float2* tw, int tid) {
  dftB_rows<N, LD, NK, INV, B, AS>(io, tmp, tw, tid);
  __syncthreads();
  dftB_cols<N, LD, NK, INV, B, AS>(tmp, io, tw, tid);
  __syncthreads();
}

// ---------- Radix 40 = 8 x 5 (2D, LD 41, in-place io with scratch T) ----------
// n = 5*n1 + n2 (n1 in [0,8), n2 in [0,5)); k = k1 + 8*k2 (k1 in [0,8), k2 in [0,5))
// Stage A: Y[n2*8+k1] = tw[n2*k1] * sum_{n1} x[5*n1+n2] * w8^{n1*k1},  w8^{k1} = tw[5*k1]
// Stage B: X[k1+8*k2] = sum_{n2} Y[n2*8+k1] * w5^{n2*k2},            w5^{k2} = tw[8*k2]
template<bool INV>
__device__ __forceinline__ void r40_rowsA(const float2* __restrict__ io, float2* __restrict__ T,
                                          const float2* __restrict__ tw, int tid) {
  if (tid < 200) {
    const int r = tid / 5, n2 = tid - 5 * r;
    const float2* base = io + r * 41 + n2;
    float xr[8], xi[8], ar[8], ai[8];
#pragma unroll
    for (int k1 = 0; k1 < 8; ++k1) {
      float2 w = tw[5 * k1];
      xr[k1] = w.x; xi[k1] = INV ? -w.y : w.y;
    }
    float2 v = base[35];
#pragma unroll
    for (int k1 = 0; k1 < 8; ++k1) { ar[k1] = v.x; ai[k1] = v.y; }
#pragma unroll
    for (int n1 = 6; n1 >= 0; --n1) {
      v = base[5 * n1];
#pragma unroll
      for (int k1 = 0; k1 < 8; ++k1) {
        float nr = fmaf(ar[k1], xr[k1], fmaf(-ai[k1], xi[k1], v.x));
        float ni = fmaf(ar[k1], xi[k1], fmaf(ai[k1], xr[k1], v.y));
        ar[k1] = nr; ai[k1] = ni;
      }
    }
    float2* o = T + r * 41 + n2 * 8;
#pragma unroll
    for (int k1 = 0; k1 < 8; ++k1) {
      float2 w = tw[n2 * k1];            // n2*k1 <= 28 < 40
      float wy = INV ? -w.y : w.y;
      o[k1] = make_float2(ar[k1] * w.x - ai[k1] * wy, ar[k1] * wy + ai[k1] * w.x);
    }
  }
}

template<bool INV>
__device__ __forceinline__ void r40_rowsB(const float2* __restrict__ T, float2* __restrict__ io,
                                          const float2* __restrict__ tw, int tid) {
  for (int u = tid; u < 320; u += NTHR) {
    const int r = u >> 3, k1 = u & 7;
    const float2* base = T + r * 41 + k1;
    float xr[5], xi[5], ar[5], ai[5];
#pragma unroll
    for (int k2 = 0; k2 < 5; ++k2) {
      float2 w = tw[8 * k2];
      xr[k2] = w.x; xi[k2] = INV ? -w.y : w.y;
    }
    float2 v = base[32];
#pragma unroll
    for (int k2 = 0; k2 < 5; ++k2) { ar[k2] = v.x; ai[k2] = v.y; }
#pragma unroll
    for (int n2 = 3; n2 >= 0; --n2) {
      v = base[n2 * 8];
#pragma unroll
      for (int k2 = 0; k2 < 5; ++k2) {
        float nr = fmaf(ar[k2], xr[k2], fmaf(-ai[k2], xi[k2], v.x));
        float ni = fmaf(ar[k2], xi[k2], fmaf(ai[k2], xr[k2], v.y));
        ar[k2] = nr; ai[k2] = ni;
      }
    }
    float2* o = io + r * 41 + k1;
#pragma unroll
    for (int k2 = 0; k2 < 5; ++k2) o[8 * k2] = make_float2(ar[k2], ai[k2]);
  }
}

template<bool INV>
__device__ __forceinline__ void r40_colsA(const float2* __restrict__ io, float2* __restrict__ T,
                                          const float2* __restrict__ tw, int tid) {
  if (tid < 200) {
    const int n2 = tid / 40, c = tid - 40 * n2;
    const float2* base = io + n2 * 41 + c;
    float xr[8], xi[8], ar[8], ai[8];
#pragma unroll
    for (int k1 = 0; k1 < 8; ++k1) {
      float2 w = tw[5 * k1];
      xr[k1] = w.x; xi[k1] = INV ? -w.y : w.y;
    }
    float2 v = base[35 * 41];
#pragma unroll
    for (int k1 = 0; k1 < 8; ++k1) { ar[k1] = v.x; ai[k1] = v.y; }
#pragma unroll
    for (int n1 = 6; n1 >= 0; --n1) {
      v = base[5 * n1 * 41];
#pragma unroll
      for (int k1 = 0; k1 < 8; ++k1) {
        float nr = fmaf(ar[k1], xr[k1], fmaf(-ai[k1], xi[k1], v.x));
        float ni = fmaf(ar[k1], xi[k1], fmaf(ai[k1], xr[k1], v.y));
        ar[k1] = nr; ai[k1] = ni;
      }
    }
    float2* o = T + n2 * 8 * 41 + c;
#pragma unroll
    for (int k1 = 0; k1 < 8; ++k1) {
      float2 w = tw[n2 * k1];
      float wy = INV ? -w.y : w.y;
      o[k1 * 41] = make_float2(ar[k1] * w.x - ai[k1] * wy, ar[k1] * wy + ai[k1] * w.x);
    }
  }
}

template<bool INV>
__device__ __forceinline__ void r40_colsB(const float2* __restrict__ T, float2* __restrict__ io,
                                          const float2* __restrict__ tw, int tid) {
  constexpr float scale = INV ? (1.f / 1600.f) : 1.f;
  for (int u = tid; u < 320; u += NTHR) {
    const int k1 = u / 40, c = u - 40 * k1;
    const float2* base = T + k1 * 41 + c;
    float xr[5], xi[5], ar[5], ai[5];
#pragma unroll
    for (int k2 = 0; k2 < 5; ++k2) {
      float2 w = tw[8 * k2];
      xr[k2] = w.x; xi[k2] = INV ? -w.y : w.y;
    }
    float2 v = base[4 * 8 * 41];
#pragma unroll
    for (int k2 = 0; k2 < 5; ++k2) { ar[k2] = v.x; ai[k2] = v.y; }
#pragma unroll
    for (int n2 = 3; n2 >= 0; --n2) {
      v = base[n2 * 8 * 41];
#pragma unroll
      for (int k2 = 0; k2 < 5; ++k2) {
        float nr = fmaf(ar[k2], xr[k2], fmaf(-ai[k2], xi[k2], v.x));
        float ni = fmaf(ar[k2], xi[k2], fmaf(ai[k2], xr[k2], v.y));
        ar[k2] = nr; ai[k2] = ni;
      }
    }
    float2* o = io + k1 * 41 + c;
#pragma unroll
    for (int k2 = 0; k2 < 5; ++k2)
      o[8 * k2 * 41] = make_float2(ar[k2] * scale, ai[k2] * scale);
  }
}

// caller must __syncthreads() after filling io
template<bool INV>
__device__ __forceinline__ void radix40(float2* io, float2* T, const float2* tw, int tid) {
  r40_rowsA<INV>(io, T, tw, tid);
  __syncthreads();
  r40_rowsB<INV>(T, io, tw, tid);
  __syncthreads();
  r40_colsA<INV>(io, T, tw, tid);
  __syncthreads();
  r40_colsB<INV>(T, io, tw, tid);
  __syncthreads();
}

// ---------- Kernel 1: Morlet filter bank (f32, on device) ----------
// filt layout (floats):
//   [0]     phi0f  100*16  fold4-gathered phi0-hat, pre-scaled 1/16
//   [1600]  phi1f  100*4   fold2-gathered phi1-hat (20-grid), pre-scaled 1/4
//   [2000]  psi0   8*1600  linear psi0-hat
//   [14800] psi1f  8*400*4 fold2-gathered psi1-hat, pre-scaled 1/4
__global__ __launch_bounds__(NTHR) void k_filters(float* __restrict__ filt) {
  const int fid = blockIdx.x;   // 0=phi, 1..8=psi0 t, 9..16=psi1 t
  const int tid = threadIdx.x;

  __shared__ float2 WV[40 * 41];
  __shared__ float  EV[1600];
  __shared__ float2 T[40 * 41];
  __shared__ float2 tw40[40];
  __shared__ float  sred[3][4];
  __shared__ float  Kc[2];

  double sigma, theta, xi, slant; int morlet;
  if (fid == 0)      { sigma = 3.2; theta = 0.0; xi = 0.0;                  slant = 1.0; morlet = 0; }
  else if (fid <= 8) { int t = fid - 1; sigma = 0.8; theta = (3 - t) * M_PI / 8.0; xi = 3.0 * M_PI / 4.0; slant = 0.5; morlet = 1; }
  else               { int t = fid - 9; sigma = 1.6; theta = (3 - t) * M_PI / 8.0; xi = 3.0 * M_PI / 8.0; slant = 0.5; morlet = 1; }

  const double ctd = cos(theta), std_ = sin(theta);
  const double sl2 = slant * slant;
  const double inv2s = 1.0 / (2.0 * sigma * sigma);
  const float ca = (float)((ctd * ctd + sl2 * std_ * std_) * inv2s);
  const float cb = (float)((ctd * std_ * (1.0 - sl2)) * inv2s);
  const float cd = (float)((std_ * std_ + sl2 * ctd * ctd) * inv2s);
  const float rnorm = (float)(slant / (2.0 * M_PI * sigma * sigma));
  const float ct = (float)ctd, st = (float)std_;
  const float xif = (float)xi;

  float swr = 0.f, swi = 0.f, ser = 0.f;
  for (int o = tid; o < 1600; o += NTHR) {
    int xr = o / 40, yc = o - 40 * xr;
    float wr = 0.f, wi = 0.f, er = 0.f;
    for (int ex = -2; ex <= 2; ++ex) {
      for (int ey = -2; ey <= 2; ++ey) {
        float xg = (float)xr + ex * 40.f, yg = (float)yc + ey * 40.f;
        float e = expf(-(ca * xg * xg + 2.f * cb * xg * yg + cd * yg * yg));
        float ang = xif * (xg * ct + yg * st);
        float s, c;
        sincosf(ang, &s, &c);
        wr = fmaf(e, c, wr); wi = fmaf(e, s, wi); er += e;
      }
    }
    wr *= rnorm; wi *= rnorm; er *= rnorm;
    WV[xr * 41 + yc] = make_float2(wr, wi);
    EV[o] = er;
    swr += wr; swi += wi; ser += er;
  }
  for (int off = 32; off > 0; off >>= 1) {
    swr += __shfl_down(swr, off);
    swi += __shfl_down(swi, off);
    ser += __shfl_down(ser, off);
  }
  int lane = tid & 63, w = tid >> 6;
  if (lane == 0) { sred[0][w] = swr; sred[1][w] = swi; sred[2][w] = ser; }
  __syncthreads();
  if (tid == 0) {
    float A = 0, B = 0, C = 0;
    for (int i = 0; i < 4; ++i) { A += sred[0][i]; B += sred[1][i]; C += sred[2][i]; }
    Kc[0] = A / C; Kc[1] = B / C;
  }
  init_tw(tw40, 40, tid);
  __syncthreads();
  if (morlet) {
    for (int o = tid; o < 1600; o += NTHR) {
      int i = o / 40, j = o - 40 * i;
      float e = EV[o];
      WV[i * 41 + j].x -= Kc[0] * e;
      WV[i * 41 + j].y -= Kc[1] * e;
    }
  }
  __syncthreads();
  dft2dB<40, 41, 8, false, 1, 0>(WV, T, tw40, tid);

  if (fid == 0) {
    // phi0f: fold4 gather, pre-scale 1/16
    for (int o = tid; o < 1600; o += NTHR) {
      int q = o >> 4, j = o & 15;
      int q1 = q / 10, q2 = q - 10 * q1;
      int a2 = j >> 2, b2 = j & 3;
      filt[o] = WV[(q1 + 10 * a2) * 41 + (q2 + 10 * b2)].x * (1.f / 16.f);
    }
    // phi1 on 20-grid into EV
    for (int m = tid; m < 400; m += NTHR) {
      int m1 = m / 20, m2 = m - 20 * m1;
      EV[m] = 0.25f * (WV[m1 * 41 + m2].x + WV[(m1 + 20) * 41 + m2].x +
                       WV[m1 * 41 + m2 + 20].x + WV[(m1 + 20) * 41 + m2 + 20].x);
    }
    __syncthreads();
    // phi1f: fold2 gather of EV, pre-scale 1/4
    for (int o = tid; o < 400; o += NTHR) {
      int q = o >> 2, j = o & 3;
      int q1 = q / 10, q2 = q - 10 * q1;
      int a2 = j >> 1, b2 = j & 1;
      filt[1600 + o] = EV[(q1 + 10 * a2) * 20 + (q2 + 10 * b2)] * 0.25f;
    }
  } else if (fid <= 8) {
    int t = fid - 1;
    for (int o = tid; o < 1600; o += NTHR) {
      int i = o / 40, j = o - 40 * i;
      filt[2000 + t * 1600 + o] = WV[i * 41 + j].x;
    }
  } else {
    int t = fid - 9;
    for (int q = tid; q < 400; q += NTHR) {
      int q1 = q / 20, q2 = q - 20 * q1;
      int base = q1 * 41 + q2;
      float* o = filt + 14800 + t * 1600 + q * 4;
      o[0] = WV[base].x * 0.25f;
      o[1] = WV[base + 20].x * 0.25f;
      o[2] = WV[base + 820].x * 0.25f;
      o[3] = WV[base + 840].x * 0.25f;
    }
  }
}

// ---------- Kernel 2: pad + fft40(xp) -> xf; S0 ----------
__global__ __launch_bounds__(NTHR) void k_fftx(const float* __restrict__ x,
                                               const float* __restrict__ filt,
                                               float2* __restrict__ xf_g,
                                               float* __restrict__ f) {
  const int bc = blockIdx.x;
  const int b = bc / 3, c = bc - 3 * b;
  const int tid = threadIdx.x;

  __shared__ float2 A[40 * 41], T[40 * 41];
  __shared__ float2 P[110];
  __shared__ float2 tw40[40], tw10[10];

  init_tw(tw40, 40, tid);
  init_tw(tw10, 10, tid);

  const float* xb = x + (size_t)bc * 1024;
  for (int o = tid; o < 1600; o += NTHR) {
    int i = o / 40, j = o - 40 * i;
    int si = reflect32(i - 4), sj = reflect32(j - 4);
    A[i * 41 + j] = make_float2(xb[si * 32 + sj], 0.f);
  }
  __syncthreads();
  radix40<false>(A, T, tw40, tid);
  for (int o = tid; o < 1600; o += NTHR) {
    int i = o / 40, j = o - 40 * i;
    xf_g[(size_t)bc * 1600 + o] = A[i * 41 + j];
  }

  // S0 = ifft2_10( fold4( xf * phi0 ) ), real, [1:-1]
  const float4* ph0f4 = (const float4*)filt;
  for (int q = tid; q < 100; q += NTHR) {
    int q1 = q / 10, q2 = q - 10 * q1;
    int base = q1 * 41 + q2;
    float re = 0.f, im = 0.f;
#pragma unroll
    for (int a2 = 0; a2 < 4; ++a2) {
      float4 pf = ph0f4[q * 4 + a2];
      float2 v0 = A[base + a2 * 410];
      float2 v1 = A[base + a2 * 410 + 10];
      float2 v2 = A[base + a2 * 410 + 20];
      float2 v3 = A[base + a2 * 410 + 30];
      re = fmaf(v0.x, pf.x, fmaf(v1.x, pf.y, fmaf(v2.x, pf.z, fmaf(v3.x, pf.w, re))));
      im = fmaf(v0.y, pf.x, fmaf(v1.y, pf.y, fmaf(v2.y, pf.z, fmaf(v3.y, pf.w, im))));
    }
    P[q1 * 11 + q2] = make_float2(re, im);
  }
  __syncthreads();
  dft2dB<10, 11, 1, true, 1, 0>(P, T, tw10, tid);
  float* fb = f + (size_t)b * 15552 + c * 5184;
  if (tid < 64) {
    int i = tid >> 3, j = tid & 7;
    fb[tid] = P[(i + 1) * 11 + (j + 1)].x;
  }
}

// ---------- Kernel 3: per (b,c,t): S1b, U1a, S1a, 4 paired S2 ----------
__global__ __launch_bounds__(NTHR) void k_main(const float2* __restrict__ xf_g,
                                               const float* __restrict__ filt,
                                               float* __restrict__ f) {
  const int blk = blockIdx.x;           // 384*8
  const int t = blk & 7;
  const int bc = blk >> 3;
  const int b = bc / 3, c = bc - 3 * b;
  const int tid = threadIdx.x;

  __shared__ float2 A[40 * 41];         // xf, then Ua_f
  __shared__ float2 T[40 * 41];         // scratch
  __shared__ float2 C[2 * 420];         // 20x20 io (LD 21, up to batch 2)
  __shared__ float2 P[110];             // S1a/S1b packed 10x10
  __shared__ float2 P4[4 * 110];        // deferred order-2 10x10 inputs
  __shared__ float2 tw40[40], tw20[20], tw10[10];

  const float4* ph0f4 = (const float4*)filt;                 // 100*4 float4
  const float4* ph1f4 = (const float4*)(filt + 1600);        // 100 float4
  const float*  psi0  = filt + 2000;
  const float4* ps1f4 = (const float4*)(filt + 14800);       // 8*400 float4

  init_tw(tw40, 40, tid);
  init_tw(tw20, 20, tid);
  init_tw(tw10, 10, tid);

  const float2* xf = xf_g + (size_t)bc * 1600;
  for (int o = tid; o < 1600; o += NTHR) {
    int i = o / 40, j = o - 40 * i;
    A[i * 41 + j] = xf[o];
  }
  __syncthreads();

  float* fb = f + (size_t)b * 15552 + c * 5184;

  // ---- S1b: fold2(xf*psi1[t]) -> ifft20 -> |.| -> fft20 -> fold2(phi1) -> P (rotated)
  for (int q = tid; q < 400; q += NTHR) {
    int q1 = q / 20, q2 = q - 20 * q1;
    int base = q1 * 41 + q2;
    float4 pf = ps1f4[t * 400 + q];
    float2 v0 = A[base], v1 = A[base + 20], v2 = A[base + 820], v3 = A[base + 840];
    float re = fmaf(v0.x, pf.x, fmaf(v1.x, pf.y, fmaf(v2.x, pf.z, v3.x * pf.w)));
    float im = fmaf(v0.y, pf.x, fmaf(v1.y, pf.y, fmaf(v2.y, pf.z, v3.y * pf.w)));
    C[q1 * 21 + q2] = make_float2(re, im);
  }
  __syncthreads();
  dft2dB<20, 21, 2, true, 1, 420>(C, T, tw20, tid);
  for (int o = tid; o < 400; o += NTHR) {
    int i = o / 20, j = o - 20 * i;
    float2 z = C[i * 21 + j];
    C[i * 21 + j] = make_float2(sqrtf(fmaf(z.x, z.x, z.y * z.y)), 0.f);
  }
  __syncthreads();
  dft2dB<20, 21, 2, false, 1, 420>(C, T, tw20, tid);
  for (int q = tid; q < 100; q += NTHR) {
    int q1 = q / 10, q2 = q - 10 * q1;
    int base = q1 * 21 + q2;
    float4 pf = ph1f4[q];
    float2 v0 = C[base], v1 = C[base + 10], v2 = C[base + 210], v3 = C[base + 220];
    float re = fmaf(v0.x, pf.x, fmaf(v1.x, pf.y, fmaf(v2.x, pf.z, v3.x * pf.w)));
    float im = fmaf(v0.y, pf.x, fmaf(v1.y, pf.y, fmaf(v2.y, pf.z, v3.y * pf.w)));
    P[q1 * 11 + q2] = make_float2(-im, re);   // i * (S1b lowpass spectrum)
  }

  // ---- 40-pt path: A = xf*psi0[t]; ifft40; |.|; fft40 -> Ua_f
  const float* ps0 = psi0 + t * 1600;
  __syncthreads();
  for (int o = tid; o < 1600; o += NTHR) {
    int i = o / 40, j = o - 40 * i;
    float p = ps0[o];
    float2 v = A[i * 41 + j];
    A[i * 41 + j] = make_float2(v.x * p, v.y * p);
  }
  __syncthreads();
  radix40<true>(A, T, tw40, tid);
  for (int o = tid; o < 1600; o += NTHR) {
    int i = o / 40, j = o - 40 * i;
    float2 z = A[i * 41 + j];
    A[i * 41 + j] = make_float2(sqrtf(fmaf(z.x, z.x, z.y * z.y)), 0.f);
  }
  __syncthreads();
  radix40<false>(A, T, tw40, tid);

  // ---- S1a fold4 -> accumulate into P (pack with rotated S1b)
  for (int q = tid; q < 100; q += NTHR) {
    int q1 = q / 10, q2 = q - 10 * q1;
    int base = q1 * 41 + q2;
    float re = 0.f, im = 0.f;
#pragma unroll
    for (int a2 = 0; a2 < 4; ++a2) {
      float4 pf = ph0f4[q * 4 + a2];
      float2 v0 = A[base + a2 * 410];
      float2 v1 = A[base + a2 * 410 + 10];
      float2 v2 = A[base + a2 * 410 + 20];
      float2 v3 = A[base + a2 * 410 + 30];
      re = fmaf(v0.x, pf.x, fmaf(v1.x, pf.y, fmaf(v2.x, pf.z, fmaf(v3.x, pf.w, re))));
      im = fmaf(v0.y, pf.x, fmaf(v1.y, pf.y, fmaf(v2.y, pf.z, fmaf(v3.y, pf.w, im))));
    }
    float2 prev = P[q1 * 11 + q2];
    P[q1 * 11 + q2] = make_float2(prev.x + re, prev.y + im);
  }
  __syncthreads();
  dft2dB<10, 11, 1, true, 1, 0>(P, T, tw10, tid);
  if (tid < 64) {
    int i = tid >> 3, j = tid & 7;
    float2 v = P[(i + 1) * 11 + (j + 1)];
    fb[(1 + t) * 64 + tid] = v.x;   // S1a
    fb[(9 + t) * 64 + tid] = v.y;   // S1b
  }

  // ---- order 2: pairs (2p, 2p+1); pack real U2 pair; defer ifft10s
  for (int p = 0; p < 4; ++p) {
    __syncthreads();
    for (int u = tid; u < 800; u += NTHR) {
      int a = (u >= 400) ? 1 : 0;
      int q = u - 400 * a;
      int q1 = q / 20, q2 = q - 20 * q1;
      int base = q1 * 41 + q2;
      float4 pf = ps1f4[(2 * p + a) * 400 + q];
      float2 v0 = A[base], v1 = A[base + 20], v2 = A[base + 820], v3 = A[base + 840];
      float re = fmaf(v0.x, pf.x, fmaf(v1.x, pf.y, fmaf(v2.x, pf.z, v3.x * pf.w)));
      float im = fmaf(v0.y, pf.x, fmaf(v1.y, pf.y, fmaf(v2.y, pf.z, v3.y * pf.w)));
      C[a * 420 + q1 * 21 + q2] = make_float2(re, im);
    }
    __syncthreads();
    dft2dB<20, 21, 2, true, 2, 420>(C, T, tw20, tid);
    for (int o = tid; o < 400; o += NTHR) {
      int i = o / 20, j = o - 20 * i;
      int idx = i * 21 + j;
      float2 z0 = C[idx], z1 = C[420 + idx];
      C[idx] = make_float2(sqrtf(fmaf(z0.x, z0.x, z0.y * z0.y)),
                           sqrtf(fmaf(z1.x, z1.x, z1.y * z1.y)));
    }
    __syncthreads();
    dft2dB<20, 21, 2, false, 1, 420>(C, T, tw20, tid);
    for (int q = tid; q < 100; q += NTHR) {
      int q1 = q / 10, q2 = q - 10 * q1;
      int base = q1 * 21 + q2;
      float4 pf = ph1f4[q];
      float2 v0 = C[base], v1 = C[base + 10], v2 = C[base + 210], v3 = C[base + 220];
      float re = fmaf(v0.x, pf.x, fmaf(v1.x, pf.y, fmaf(v2.x, pf.z, v3.x * pf.w)));
      float im = fmaf(v0.y, pf.x, fmaf(v1.y, pf.y, fmaf(v2.y, pf.z, v3.y * pf.w)));
      P4[p * 110 + q1 * 11 + q2] = make_float2(re, im);
    }
  }
  __syncthreads();
  dft2dB<10, 11, 1, true, 4, 110>(P4, T, tw10, tid);
  {
    int p = tid >> 6, o = tid & 63;      // 256 = 4*64 exactly
    int i = o >> 3, j = o & 7;
    float2 v = P4[p * 110 + (i + 1) * 11 + (j + 1)];
    fb[(17 + t * 8 + 2 * p) * 64 + o] = v.x;
    fb[(17 + t * 8 + 2 * p + 1) * 64 + o] = v.y;
  }
}

// ---------- Kernel 4: BN stats over batch ----------
__global__ __launch_bounds__(NTHR) void k_bn(const float* __restrict__ f,
                                             float* __restrict__ mu,
                                             float* __restrict__ rstd) {
  int col = blockIdx.x * NTHR + threadIdx.x;
  if (col >= 15552) return;
  double s = 0.0, s2 = 0.0;
  for (int b = 0; b < 128; ++b) {
    float v = f[(size_t)b * 15552 + col];
    s += v; s2 += (double)v * v;
  }
  double m = s / 128.0;
  double var = s2 / 128.0 - m * m;
  mu[col] = (float)m;
  rstd[col] = (float)(1.0 / sqrt(var + 1e-5));
}

// ---------- Kernel 5: fused BN-apply + relu + collapsed ToeplitzLike (first 10 outputs) ----------
__global__ __launch_bounds__(NTHR) void k_out(const float* __restrict__ f,
                                              const float* __restrict__ mu,
                                              const float* __restrict__ rstd,
                                              const float* __restrict__ gamma,
                                              const float* __restrict__ beta,
                                              const float* __restrict__ Gm,
                                              const float* __restrict__ Hm,
                                              float* __restrict__ out) {
  const int b = blockIdx.x;
  const int tid = threadIdx.x;
  const float* fbp = f + (size_t)b * 15552;

  __shared__ float sg[NTHR + 10];
  float acc[40];
#pragma unroll
  for (int i = 0; i < 40; ++i) acc[i] = 0.f;

  for (int base = 0; base < 15552; base += NTHR) {
    int j = base + tid;
    float v = 0.f;
    if (j < 15552) {
      v = (fbp[j] - mu[j]) * rstd[j] * gamma[j] + beta[j];
      v = v > 0.f ? v : 0.f;
    }
    sg[tid] = v;
    if (tid < 10) {
      int j2 = base + NTHR + tid;
      float v2 = 0.f;
      if (j2 < 15552) {
        v2 = (fbp[j2] - mu[j2]) * rstd[j2] * gamma[j2] + beta[j2];
        v2 = v2 > 0.f ? v2 : 0.f;
      }
      sg[NTHR + tid] = v2;
    }
    __syncthreads();
    if (j < 15552) {
      float h[4];
#pragma unroll
      for (int r = 0; r < 4; ++r) h[r] = Hm[r * 15552 + j];
#pragma unroll
      for (int m = 0; m < 10; ++m) {
        float gv = sg[tid + m];
#pragma unroll
        for (int r = 0; r < 4; ++r) acc[r * 10 + m] = fmaf(h[r], gv, acc[r * 10 + m]);
      }
    }
    __syncthreads();
  }
#pragma unroll
  for (int i = 0; i < 40; ++i)
    for (int off = 32; off > 0; off >>= 1)
      acc[i] += __shfl_down(acc[i], off);

  __shared__ float red[4][40];
  __shared__ float Tm[40];
  int lane = tid & 63, w = tid >> 6;
  if (lane == 0) {
#pragma unroll
    for (int i = 0; i < 40; ++i) red[w][i] = acc[i];
  }
  __syncthreads();
  if (tid < 40) Tm[tid] = red[0][tid] + red[1][tid] + red[2][tid] + red[3][tid];
  __syncthreads();
  if (tid < 10) {
    float y = 0.f;
    for (int r = 0; r < 4; ++r)
      for (int m = 0; m <= tid; ++m)
        y += Gm[r * 15552 + (tid - m)] * Tm[r * 10 + m];
    out[b * 10 + tid] = y;
  }
}

extern "C" void kernel_launch(void* const* d_in, const int* in_sizes, int n_in,
                              void* d_out, int out_size, void* d_ws, size_t ws_size,
                              hipStream_t stream) {
  (void)in_sizes; (void)n_in; (void)out_size; (void)ws_size;
  const float* x     = (const float*)d_in[0];   // (128,3,32,32)
  const float* gamma = (const float*)d_in[1];   // (15552,)
  const float* beta  = (const float*)d_in[2];   // (15552,)
  const float* G     = (const float*)d_in[3];   // (4,15552)
  const float* H     = (const float*)d_in[4];   // (4,15552)
  float* out = (float*)d_out;                   // (128,10)

  float* ws   = (float*)d_ws;
  float* filt = ws;                         // 27600
  float* xf   = filt + 27600;               // 384*1600*2 = 1228800
  float* f    = xf + 1228800;               // 128*15552 = 1990656
  float* mu   = f + 1990656;                // 15552
  float* rstd = mu + 15552;                 // 15552

  k_filters<<<17, NTHR, 0, stream>>>(filt);
  k_fftx<<<384, NTHR, 0, stream>>>(x, filt, (float2*)xf, f);
  k_main<<<3072, NTHR, 0, stream>>>((const float2*)xf, filt, f);
  k_bn<<<61, NTHR, 0, stream>>>(f, mu, rstd);
  k_out<<<128, NTHR, 0, stream>>>(f, mu, rstd, gamma, beta, G, H, out);
}

// Round 8
// 335.246 us; speedup vs baseline: 2.5978x; 1.1398x over previous
//
#include <hip/hip_runtime.h>
#include <math.h>

#define NTHR 256

__device__ __forceinline__ int reflect32(int v) {
  if (v < 0) v = -v;
  if (v > 31) v = 62 - v;
  return v;
}

__device__ __forceinline__ void init_tw(float2* tw, int N, int tid) {
  for (int j = tid; j < N; j += NTHR) {
    float s, c;
    sincosf(-2.0f * (float)M_PI * (float)j / (float)N, &s, &c);
    tw[j] = make_float2(c, s);
  }
}

// ---------- Horner DFT passes (batched) — 20-pt (S1b), 10-pt, filters ----------
template<int N, int LD, int NK, bool INV, int B, int AS>
__device__ __forceinline__ void dftB_rows(const float2* __restrict__ io,
                                          float2* __restrict__ tmp,
                                          const float2* __restrict__ tw, int tid) {
  constexpr int G = N / NK;
  constexpr int UNITS = B * N * G;
  for (int u = tid; u < UNITS; u += NTHR) {
    const int a = u / (N * G);
    const int rem = u - a * (N * G);
    const int r = rem / G, kg = rem - G * r;
    float xr[NK], xi[NK], ar[NK], ai[NK];
#pragma unroll
    for (int j = 0; j < NK; ++j) {
      float2 w = tw[kg * NK + j];
      xr[j] = w.x; xi[j] = INV ? -w.y : w.y;
    }
    const float2* row = io + a * AS + r * LD;
    float2 v = row[N - 1];
#pragma unroll
    for (int j = 0; j < NK; ++j) { ar[j] = v.x; ai[j] = v.y; }
#pragma unroll 2
    for (int cc = N - 2; cc >= 0; --cc) {
      v = row[cc];
#pragma unroll
      for (int j = 0; j < NK; ++j) {
        float nr = fmaf(ar[j], xr[j], fmaf(-ai[j], xi[j], v.x));
        float ni = fmaf(ar[j], xi[j], fmaf(ai[j], xr[j], v.y));
        ar[j] = nr; ai[j] = ni;
      }
    }
    float2* orow = tmp + a * AS + r * LD + kg * NK;
#pragma unroll
    for (int j = 0; j < NK; ++j) orow[j] = make_float2(ar[j], ai[j]);
  }
}

template<int N, int LD, int NK, bool INV, int B, int AS>
__device__ __forceinline__ void dftB_cols(const float2* __restrict__ tmp,
                                          float2* __restrict__ io,
                                          const float2* __restrict__ tw, int tid) {
  constexpr int G = N / NK;
  constexpr int UNITS = B * N * G;
  for (int u = tid; u < UNITS; u += NTHR) {
    const int a = u / (N * G);
    const int rem = u - a * (N * G);
    const int k1g = rem / N, k2 = rem - N * k1g;
    float xr[NK], xi[NK], ar[NK], ai[NK];
#pragma unroll
    for (int j = 0; j < NK; ++j) {
      float2 w = tw[k1g * NK + j];
      xr[j] = w.x; xi[j] = INV ? -w.y : w.y;
    }
    const float2* col = tmp + a * AS + k2;
    float2 v = col[(N - 1) * LD];
#pragma unroll
    for (int j = 0; j < NK; ++j) { ar[j] = v.x; ai[j] = v.y; }
#pragma unroll 2
    for (int r = N - 2; r >= 0; --r) {
      v = col[r * LD];
#pragma unroll
      for (int j = 0; j < NK; ++j) {
        float nr = fmaf(ar[j], xr[j], fmaf(-ai[j], xi[j], v.x));
        float ni = fmaf(ar[j], xi[j], fmaf(ai[j], xr[j], v.y));
        ar[j] = nr; ai[j] = ni;
      }
    }
    constexpr float scale = INV ? (1.f / (float)(N * N)) : 1.f;
#pragma unroll
    for (int j = 0; j < NK; ++j)
      io[a * AS + (k1g * NK + j) * LD + k2] = make_float2(ar[j] * scale, ai[j] * scale);
  }
}

// caller must __syncthreads() after filling io, before calling
template<int N, int LD, int NK, bool INV, int B, int AS>
__device__ __forceinline__ void dft2dB(float2* io, float2* tmp, const float2* tw, int tid) {
  dftB_rows<N, LD, NK, INV, B, AS>(io, tmp, tw, tid);
  __syncthreads();
  dftB_cols<N, LD, NK, INV, B, AS>(tmp, io, tw, tid);
  __syncthreads();
}

// ---------- Fused register-resident 20-pt FFT, radix 4x5, literal twiddles ----------
template<bool INV>
__device__ __forceinline__ void fft20_reg(float* xr, float* xi) {
  const float C20[13] = {1.f, 0.9510565162951535f, 0.8090169943749475f, 0.5877852522924731f,
                         0.3090169943749474f, 0.f, -0.3090169943749474f, -0.5877852522924731f,
                         -0.8090169943749475f, -0.9510565162951535f, -1.f, -0.9510565162951535f,
                         -0.8090169943749475f};
  const float S20[13] = {0.f, 0.3090169943749474f, 0.5877852522924731f, 0.8090169943749475f,
                         0.9510565162951535f, 1.f, 0.9510565162951535f, 0.8090169943749475f,
                         0.5877852522924731f, 0.3090169943749474f, 0.f, -0.3090169943749474f,
                         -0.5877852522924731f};
  float ur[20], ui[20];
#pragma unroll
  for (int n2 = 0; n2 < 5; ++n2) {
    float x0r = xr[n2],      x0i = xi[n2];
    float x1r = xr[5 + n2],  x1i = xi[5 + n2];
    float x2r = xr[10 + n2], x2i = xi[10 + n2];
    float x3r = xr[15 + n2], x3i = xi[15 + n2];
    float e0r = x0r + x2r, e0i = x0i + x2i;
    float d0r = x0r - x2r, d0i = x0i - x2i;
    float e1r = x1r + x3r, e1i = x1i + x3i;
    float d1r = x1r - x3r, d1i = x1i - x3i;
    float y0r = e0r + e1r, y0i = e0i + e1i;
    float y2r = e0r - e1r, y2i = e0i - e1i;
    float y1r, y1i, y3r, y3i;
    if (INV) { y1r = d0r - d1i; y1i = d0i + d1r; y3r = d0r + d1i; y3i = d0i - d1r; }
    else     { y1r = d0r + d1i; y1i = d0i - d1r; y3r = d0r - d1i; y3i = d0i + d1r; }
    ur[n2 * 4 + 0] = y0r; ui[n2 * 4 + 0] = y0i;
    {
      float c = C20[n2], s = INV ? S20[n2] : -S20[n2];
      ur[n2 * 4 + 1] = y1r * c - y1i * s; ui[n2 * 4 + 1] = y1r * s + y1i * c;
    }
    {
      float c = C20[2 * n2], s = INV ? S20[2 * n2] : -S20[2 * n2];
      ur[n2 * 4 + 2] = y2r * c - y2i * s; ui[n2 * 4 + 2] = y2r * s + y2i * c;
    }
    {
      float c = C20[3 * n2], s = INV ? S20[3 * n2] : -S20[3 * n2];
      ur[n2 * 4 + 3] = y3r * c - y3i * s; ui[n2 * 4 + 3] = y3r * s + y3i * c;
    }
  }
  const float C5[5] = {1.f, 0.3090169943749474f, -0.8090169943749475f, -0.8090169943749475f,
                       0.3090169943749474f};
  const float S5[5] = {0.f, 0.9510565162951535f, 0.5877852522924731f, -0.5877852522924731f,
                       -0.9510565162951535f};
#pragma unroll
  for (int k1 = 0; k1 < 4; ++k1) {
    float t0r = ur[k1],      t0i = ui[k1];
    float t1r = ur[4 + k1],  t1i = ui[4 + k1];
    float t2r = ur[8 + k1],  t2i = ui[8 + k1];
    float t3r = ur[12 + k1], t3i = ui[12 + k1];
    float t4r = ur[16 + k1], t4i = ui[16 + k1];
#pragma unroll
    for (int k2 = 0; k2 < 5; ++k2) {
      float ar = t0r, ai = t0i;
      { const int j = (1 * k2) % 5; float c = C5[j], s = INV ? S5[j] : -S5[j];
        ar += t1r * c - t1i * s; ai += t1r * s + t1i * c; }
      { const int j = (2 * k2) % 5; float c = C5[j], s = INV ? S5[j] : -S5[j];
        ar += t2r * c - t2i * s; ai += t2r * s + t2i * c; }
      { const int j = (3 * k2) % 5; float c = C5[j], s = INV ? S5[j] : -S5[j];
        ar += t3r * c - t3i * s; ai += t3r * s + t3i * c; }
      { const int j = (4 * k2) % 5; float c = C5[j], s = INV ? S5[j] : -S5[j];
        ar += t4r * c - t4i * s; ai += t4r * s + t4i * c; }
      xr[k1 + 4 * k2] = ar; xi[k1 + 4 * k2] = ai;
    }
  }
}

// one pass of a batched 2D 20x20 transform on split re/im planes (LD 21, slab 420)
template<bool INV, int BATCH, bool SCALE, bool COLS>
__device__ __forceinline__ void fused20_pass(float* __restrict__ UR, float* __restrict__ UI, int tid) {
  if (tid < BATCH * 20) {
    const int a = tid / 20, q = tid % 20;
    const int off = a * 420 + (COLS ? q : q * 21);
    const int st = COLS ? 21 : 1;
    float xr[20], xi[20];
#pragma unroll
    for (int n = 0; n < 20; ++n) { xr[n] = UR[off + st * n]; xi[n] = UI[off + st * n]; }
    fft20_reg<INV>(xr, xi);
#pragma unroll
    for (int n = 0; n < 20; ++n) {
      float vr = xr[n], vi = xi[n];
      if (SCALE) { vr *= (1.f / 400.f); vi *= (1.f / 400.f); }
      UR[off + st * n] = vr; UI[off + st * n] = vi;
    }
  }
}

// fwd rows pass with inline magnitude of channel pair (2p, 2p+1) -> packed (|z0|,|z1|)
__device__ __forceinline__ void fwd20_rows_mag(const float* __restrict__ CR, const float* __restrict__ CI,
                                               float* __restrict__ FR, float* __restrict__ FI, int tid) {
  if (tid < 80) {
    const int p = tid / 20, r = tid % 20;
    const int i0 = (2 * p) * 420 + r * 21;
    const int i1 = (2 * p + 1) * 420 + r * 21;
    float xr[20], xi[20];
#pragma unroll
    for (int n = 0; n < 20; ++n) {
      float a0 = CR[i0 + n], b0 = CI[i0 + n];
      float a1 = CR[i1 + n], b1 = CI[i1 + n];
      xr[n] = sqrtf(fmaf(a0, a0, b0 * b0));
      xi[n] = sqrtf(fmaf(a1, a1, b1 * b1));
    }
    fft20_reg<false>(xr, xi);
    const int off = p * 420 + r * 21;
#pragma unroll
    for (int n = 0; n < 20; ++n) { FR[off + n] = xr[n]; FI[off + n] = xi[n]; }
  }
}

// ---------- Radix 40 = 8 x 5 (2D, LD 41, io + scratch T) ----------
template<bool INV>
__device__ __forceinline__ void r40_rowsA(const float2* __restrict__ io, float2* __restrict__ T,
                                          const float2* __restrict__ tw, int tid) {
  if (tid < 200) {
    const int r = tid / 5, n2 = tid - 5 * r;
    const float2* base = io + r * 41 + n2;
    float xr[8], xi[8], ar[8], ai[8];
#pragma unroll
    for (int k1 = 0; k1 < 8; ++k1) {
      float2 w = tw[5 * k1];
      xr[k1] = w.x; xi[k1] = INV ? -w.y : w.y;
    }
    float2 v = base[35];
#pragma unroll
    for (int k1 = 0; k1 < 8; ++k1) { ar[k1] = v.x; ai[k1] = v.y; }
#pragma unroll
    for (int n1 = 6; n1 >= 0; --n1) {
      v = base[5 * n1];
#pragma unroll
      for (int k1 = 0; k1 < 8; ++k1) {
        float nr = fmaf(ar[k1], xr[k1], fmaf(-ai[k1], xi[k1], v.x));
        float ni = fmaf(ar[k1], xi[k1], fmaf(ai[k1], xr[k1], v.y));
        ar[k1] = nr; ai[k1] = ni;
      }
    }
    float2* o = T + r * 41 + n2 * 8;
#pragma unroll
    for (int k1 = 0; k1 < 8; ++k1) {
      float2 w = tw[n2 * k1];
      float wy = INV ? -w.y : w.y;
      o[k1] = make_float2(ar[k1] * w.x - ai[k1] * wy, ar[k1] * wy + ai[k1] * w.x);
    }
  }
}

template<bool INV>
__device__ __forceinline__ void r40_rowsB(const float2* __restrict__ T, float2* __restrict__ io,
                                          const float2* __restrict__ tw, int tid) {
  for (int u = tid; u < 320; u += NTHR) {
    const int r = u >> 3, k1 = u & 7;
    const float2* base = T + r * 41 + k1;
    float xr[5], xi[5], ar[5], ai[5];
#pragma unroll
    for (int k2 = 0; k2 < 5; ++k2) {
      float2 w = tw[8 * k2];
      xr[k2] = w.x; xi[k2] = INV ? -w.y : w.y;
    }
    float2 v = base[32];
#pragma unroll
    for (int k2 = 0; k2 < 5; ++k2) { ar[k2] = v.x; ai[k2] = v.y; }
#pragma unroll
    for (int n2 = 3; n2 >= 0; --n2) {
      v = base[n2 * 8];
#pragma unroll
      for (int k2 = 0; k2 < 5; ++k2) {
        float nr = fmaf(ar[k2], xr[k2], fmaf(-ai[k2], xi[k2], v.x));
        float ni = fmaf(ar[k2], xi[k2], fmaf(ai[k2], xr[k2], v.y));
        ar[k2] = nr; ai[k2] = ni;
      }
    }
    float2* o = io + r * 41 + k1;
#pragma unroll
    for (int k2 = 0; k2 < 5; ++k2) o[8 * k2] = make_float2(ar[k2], ai[k2]);
  }
}

template<bool INV>
__device__ __forceinline__ void r40_colsA(const float2* __restrict__ io, float2* __restrict__ T,
                                          const float2* __restrict__ tw, int tid) {
  if (tid < 200) {
    const int n2 = tid / 40, c = tid - 40 * n2;
    const float2* base = io + n2 * 41 + c;
    float xr[8], xi[8], ar[8], ai[8];
#pragma unroll
    for (int k1 = 0; k1 < 8; ++k1) {
      float2 w = tw[5 * k1];
      xr[k1] = w.x; xi[k1] = INV ? -w.y : w.y;
    }
    float2 v = base[35 * 41];
#pragma unroll
    for (int k1 = 0; k1 < 8; ++k1) { ar[k1] = v.x; ai[k1] = v.y; }
#pragma unroll
    for (int n1 = 6; n1 >= 0; --n1) {
      v = base[5 * n1 * 41];
#pragma unroll
      for (int k1 = 0; k1 < 8; ++k1) {
        float nr = fmaf(ar[k1], xr[k1], fmaf(-ai[k1], xi[k1], v.x));
        float ni = fmaf(ar[k1], xi[k1], fmaf(ai[k1], xr[k1], v.y));
        ar[k1] = nr; ai[k1] = ni;
      }
    }
    float2* o = T + n2 * 8 * 41 + c;
#pragma unroll
    for (int k1 = 0; k1 < 8; ++k1) {
      float2 w = tw[n2 * k1];
      float wy = INV ? -w.y : w.y;
      o[k1 * 41] = make_float2(ar[k1] * w.x - ai[k1] * wy, ar[k1] * wy + ai[k1] * w.x);
    }
  }
}

template<bool INV>
__device__ __forceinline__ void r40_colsB(const float2* __restrict__ T, float2* __restrict__ io,
                                          const float2* __restrict__ tw, int tid) {
  constexpr float scale = INV ? (1.f / 1600.f) : 1.f;
  for (int u = tid; u < 320; u += NTHR) {
    const int k1 = u / 40, c = u - 40 * k1;
    const float2* base = T + k1 * 41 + c;
    float xr[5], xi[5], ar[5], ai[5];
#pragma unroll
    for (int k2 = 0; k2 < 5; ++k2) {
      float2 w = tw[8 * k2];
      xr[k2] = w.x; xi[k2] = INV ? -w.y : w.y;
    }
    float2 v = base[4 * 8 * 41];
#pragma unroll
    for (int k2 = 0; k2 < 5; ++k2) { ar[k2] = v.x; ai[k2] = v.y; }
#pragma unroll
    for (int n2 = 3; n2 >= 0; --n2) {
      v = base[n2 * 8 * 41];
#pragma unroll
      for (int k2 = 0; k2 < 5; ++k2) {
        float nr = fmaf(ar[k2], xr[k2], fmaf(-ai[k2], xi[k2], v.x));
        float ni = fmaf(ar[k2], xi[k2], fmaf(ai[k2], xr[k2], v.y));
        ar[k2] = nr; ai[k2] = ni;
      }
    }
    float2* o = io + k1 * 41 + c;
#pragma unroll
    for (int k2 = 0; k2 < 5; ++k2)
      o[8 * k2 * 41] = make_float2(ar[k2] * scale, ai[k2] * scale);
  }
}

template<bool INV>
__device__ __forceinline__ void radix40(float2* io, float2* T, const float2* tw, int tid) {
  r40_rowsA<INV>(io, T, tw, tid);
  __syncthreads();
  r40_rowsB<INV>(T, io, tw, tid);
  __syncthreads();
  r40_colsA<INV>(io, T, tw, tid);
  __syncthreads();
  r40_colsB<INV>(T, io, tw, tid);
  __syncthreads();
}

// ---------- Kernel 1: Morlet filter bank (f32, on device) ----------
// filt layout (floats):
//   [0]     phi0f  100*16  fold4-gathered phi0-hat, pre-scaled 1/16
//   [1600]  phi1f  100*4   fold2-gathered phi1-hat (20-grid), pre-scaled 1/4
//   [2000]  psi0   8*1600  linear psi0-hat
//   [14800] psi1f  8*400*4 fold2-gathered psi1-hat, pre-scaled 1/4
__global__ __launch_bounds__(NTHR) void k_filters(float* __restrict__ filt) {
  const int fid = blockIdx.x;
  const int tid = threadIdx.x;

  __shared__ float2 WV[40 * 41];
  __shared__ float  EV[1600];
  __shared__ float2 T[40 * 41];
  __shared__ float2 tw40[40];
  __shared__ float  sred[3][4];
  __shared__ float  Kc[2];

  double sigma, theta, xi, slant; int morlet;
  if (fid == 0)      { sigma = 3.2; theta = 0.0; xi = 0.0;                  slant = 1.0; morlet = 0; }
  else if (fid <= 8) { int t = fid - 1; sigma = 0.8; theta = (3 - t) * M_PI / 8.0; xi = 3.0 * M_PI / 4.0; slant = 0.5; morlet = 1; }
  else               { int t = fid - 9; sigma = 1.6; theta = (3 - t) * M_PI / 8.0; xi = 3.0 * M_PI / 8.0; slant = 0.5; morlet = 1; }

  const double ctd = cos(theta), std_ = sin(theta);
  const double sl2 = slant * slant;
  const double inv2s = 1.0 / (2.0 * sigma * sigma);
  const float ca = (float)((ctd * ctd + sl2 * std_ * std_) * inv2s);
  const float cb = (float)((ctd * std_ * (1.0 - sl2)) * inv2s);
  const float cd = (float)((std_ * std_ + sl2 * ctd * ctd) * inv2s);
  const float rnorm = (float)(slant / (2.0 * M_PI * sigma * sigma));
  const float ct = (float)ctd, st = (float)std_;
  const float xif = (float)xi;

  float swr = 0.f, swi = 0.f, ser = 0.f;
  for (int o = tid; o < 1600; o += NTHR) {
    int xr = o / 40, yc = o - 40 * xr;
    float wr = 0.f, wi = 0.f, er = 0.f;
    for (int ex = -2; ex <= 2; ++ex) {
      for (int ey = -2; ey <= 2; ++ey) {
        float xg = (float)xr + ex * 40.f, yg = (float)yc + ey * 40.f;
        float e = expf(-(ca * xg * xg + 2.f * cb * xg * yg + cd * yg * yg));
        float ang = xif * (xg * ct + yg * st);
        float s, c;
        sincosf(ang, &s, &c);
        wr = fmaf(e, c, wr); wi = fmaf(e, s, wi); er += e;
      }
    }
    wr *= rnorm; wi *= rnorm; er *= rnorm;
    WV[xr * 41 + yc] = make_float2(wr, wi);
    EV[o] = er;
    swr += wr; swi += wi; ser += er;
  }
  for (int off = 32; off > 0; off >>= 1) {
    swr += __shfl_down(swr, off);
    swi += __shfl_down(swi, off);
    ser += __shfl_down(ser, off);
  }
  int lane = tid & 63, w = tid >> 6;
  if (lane == 0) { sred[0][w] = swr; sred[1][w] = swi; sred[2][w] = ser; }
  __syncthreads();
  if (tid == 0) {
    float A = 0, B = 0, C = 0;
    for (int i = 0; i < 4; ++i) { A += sred[0][i]; B += sred[1][i]; C += sred[2][i]; }
    Kc[0] = A / C; Kc[1] = B / C;
  }
  init_tw(tw40, 40, tid);
  __syncthreads();
  if (morlet) {
    for (int o = tid; o < 1600; o += NTHR) {
      int i = o / 40, j = o - 40 * i;
      float e = EV[o];
      WV[i * 41 + j].x -= Kc[0] * e;
      WV[i * 41 + j].y -= Kc[1] * e;
    }
  }
  __syncthreads();
  dft2dB<40, 41, 8, false, 1, 0>(WV, T, tw40, tid);

  if (fid == 0) {
    for (int o = tid; o < 1600; o += NTHR) {
      int q = o >> 4, j = o & 15;
      int q1 = q / 10, q2 = q - 10 * q1;
      int a2 = j >> 2, b2 = j & 3;
      filt[o] = WV[(q1 + 10 * a2) * 41 + (q2 + 10 * b2)].x * (1.f / 16.f);
    }
    for (int m = tid; m < 400; m += NTHR) {
      int m1 = m / 20, m2 = m - 20 * m1;
      EV[m] = 0.25f * (WV[m1 * 41 + m2].x + WV[(m1 + 20) * 41 + m2].x +
                       WV[m1 * 41 + m2 + 20].x + WV[(m1 + 20) * 41 + m2 + 20].x);
    }
    __syncthreads();
    for (int o = tid; o < 400; o += NTHR) {
      int q = o >> 2, j = o & 3;
      int q1 = q / 10, q2 = q - 10 * q1;
      int a2 = j >> 1, b2 = j & 1;
      filt[1600 + o] = EV[(q1 + 10 * a2) * 20 + (q2 + 10 * b2)] * 0.25f;
    }
  } else if (fid <= 8) {
    int t = fid - 1;
    for (int o = tid; o < 1600; o += NTHR) {
      int i = o / 40, j = o - 40 * i;
      filt[2000 + t * 1600 + o] = WV[i * 41 + j].x;
    }
  } else {
    int t = fid - 9;
    for (int q = tid; q < 400; q += NTHR) {
      int q1 = q / 20, q2 = q - 20 * q1;
      int base = q1 * 41 + q2;
      float* o = filt + 14800 + t * 1600 + q * 4;
      o[0] = WV[base].x * 0.25f;
      o[1] = WV[base + 20].x * 0.25f;
      o[2] = WV[base + 820].x * 0.25f;
      o[3] = WV[base + 840].x * 0.25f;
    }
  }
}

// ---------- Kernel 2: pad + fft40(xp) -> xf; S0 ----------
__global__ __launch_bounds__(NTHR) void k_fftx(const float* __restrict__ x,
                                               const float* __restrict__ filt,
                                               float2* __restrict__ xf_g,
                                               float* __restrict__ f) {
  const int bc = blockIdx.x;
  const int b = bc / 3, c = bc - 3 * b;
  const int tid = threadIdx.x;

  __shared__ float2 A[40 * 41], T[40 * 41];
  __shared__ float2 P[110];
  __shared__ float2 tw40[40], tw10[10];

  init_tw(tw40, 40, tid);
  init_tw(tw10, 10, tid);

  const float* xb = x + (size_t)bc * 1024;
  for (int o = tid; o < 1600; o += NTHR) {
    int i = o / 40, j = o - 40 * i;
    int si = reflect32(i - 4), sj = reflect32(j - 4);
    A[i * 41 + j] = make_float2(xb[si * 32 + sj], 0.f);
  }
  __syncthreads();
  radix40<false>(A, T, tw40, tid);
  for (int o = tid; o < 1600; o += NTHR) {
    int i = o / 40, j = o - 40 * i;
    xf_g[(size_t)bc * 1600 + o] = A[i * 41 + j];
  }

  const float4* ph0f4 = (const float4*)filt;
  for (int q = tid; q < 100; q += NTHR) {
    int q1 = q / 10, q2 = q - 10 * q1;
    int base = q1 * 41 + q2;
    float re = 0.f, im = 0.f;
#pragma unroll
    for (int a2 = 0; a2 < 4; ++a2) {
      float4 pf = ph0f4[q * 4 + a2];
      float2 v0 = A[base + a2 * 410];
      float2 v1 = A[base + a2 * 410 + 10];
      float2 v2 = A[base + a2 * 410 + 20];
      float2 v3 = A[base + a2 * 410 + 30];
      re = fmaf(v0.x, pf.x, fmaf(v1.x, pf.y, fmaf(v2.x, pf.z, fmaf(v3.x, pf.w, re))));
      im = fmaf(v0.y, pf.x, fmaf(v1.y, pf.y, fmaf(v2.y, pf.z, fmaf(v3.y, pf.w, im))));
    }
    P[q1 * 11 + q2] = make_float2(re, im);
  }
  __syncthreads();
  dft2dB<10, 11, 1, true, 1, 0>(P, T, tw10, tid);
  float* fb = f + (size_t)b * 15552 + c * 5184;
  if (tid < 64) {
    int i = tid >> 3, j = tid & 7;
    fb[tid] = P[(i + 1) * 11 + (j + 1)].x;
  }
}

// ---------- Kernel 3: per (b,c,t): S1b, U1a, S1a, batch-8 order-2 ----------
__global__ __launch_bounds__(NTHR) void k_main(const float2* __restrict__ xf_g,
                                               const float* __restrict__ filt,
                                               float* __restrict__ f) {
  const int blk = blockIdx.x;           // 384*8
  const int t = blk & 7;
  const int bc = blk >> 3;
  const int b = bc / 3, c = bc - 3 * b;
  const int tid = threadIdx.x;

  // one LDS union (floats):
  // [0..3280)      A (float2[1640], LD41): xf -> Ua_f.  Later: fwd FR [0..1680) FI [1680..3360)
  // [3360..10080)  fields: CR = +3360 (8*420), CI = +6720 (8*420)
  //   phase-shared: S1b C20 @3360, T20 @4200; radix40 T40 @3360..6640;
  //                 P @6700 (110 f2), SC1 @7000 (110 f2);
  //                 order-2 P4 @3360 (440 f2), SC4 @4400 (440 f2)
  // [10080..10220) tw40 / tw20 / tw10
  __shared__ float U[10220];
  float2* A    = (float2*)U;
  float*  FR   = U;
  float*  FI   = U + 1680;
  float*  CR   = U + 3360;
  float*  CI   = U + 6720;
  float2* C20  = (float2*)(U + 3360);
  float2* T20  = (float2*)(U + 4200);
  float2* T40  = (float2*)(U + 3360);
  float2* P    = (float2*)(U + 6700);
  float2* SC1  = (float2*)(U + 7000);
  float2* P4   = (float2*)(U + 3360);
  float2* SC4  = (float2*)(U + 4400);
  float2* tw40 = (float2*)(U + 10080);
  float2* tw20 = (float2*)(U + 10160);
  float2* tw10 = (float2*)(U + 10200);

  const float4* ph0f4 = (const float4*)filt;
  const float4* ph1f4 = (const float4*)(filt + 1600);
  const float*  psi0  = filt + 2000;
  const float4* ps1f4 = (const float4*)(filt + 14800);

  init_tw(tw40, 40, tid);
  init_tw(tw20, 20, tid);
  init_tw(tw10, 10, tid);

  const float2* xf = xf_g + (size_t)bc * 1600;
  for (int o = tid; o < 1600; o += NTHR) {
    int i = o / 40, j = o - 40 * i;
    A[i * 41 + j] = xf[o];
  }
  __syncthreads();

  float* fb = f + (size_t)b * 15552 + c * 5184;

  // ---- S1b: fold2(xf*psi1[t]) -> ifft20 -> |.| -> fft20 -> fold2(phi1) -> P (rotated)
  for (int q = tid; q < 400; q += NTHR) {
    int q1 = q / 20, q2 = q - 20 * q1;
    int base = q1 * 41 + q2;
    float4 pf = ps1f4[t * 400 + q];
    float2 v0 = A[base], v1 = A[base + 20], v2 = A[base + 820], v3 = A[base + 840];
    float re = fmaf(v0.x, pf.x, fmaf(v1.x, pf.y, fmaf(v2.x, pf.z, v3.x * pf.w)));
    float im = fmaf(v0.y, pf.x, fmaf(v1.y, pf.y, fmaf(v2.y, pf.z, v3.y * pf.w)));
    C20[q1 * 21 + q2] = make_float2(re, im);
  }
  __syncthreads();
  dft2dB<20, 21, 2, true, 1, 420>(C20, T20, tw20, tid);
  for (int o = tid; o < 400; o += NTHR) {
    int i = o / 20, j = o - 20 * i;
    float2 z = C20[i * 21 + j];
    C20[i * 21 + j] = make_float2(sqrtf(fmaf(z.x, z.x, z.y * z.y)), 0.f);
  }
  __syncthreads();
  dft2dB<20, 21, 2, false, 1, 420>(C20, T20, tw20, tid);
  for (int q = tid; q < 100; q += NTHR) {
    int q1 = q / 10, q2 = q - 10 * q1;
    int base = q1 * 21 + q2;
    float4 pf = ph1f4[q];
    float2 v0 = C20[base], v1 = C20[base + 10], v2 = C20[base + 210], v3 = C20[base + 220];
    float re = fmaf(v0.x, pf.x, fmaf(v1.x, pf.y, fmaf(v2.x, pf.z, v3.x * pf.w)));
    float im = fmaf(v0.y, pf.x, fmaf(v1.y, pf.y, fmaf(v2.y, pf.z, v3.y * pf.w)));
    P[q1 * 11 + q2] = make_float2(-im, re);   // i * (S1b lowpass spectrum)
  }

  // ---- 40-pt path: A = xf*psi0[t]; ifft40; |.|; fft40 -> Ua_f
  const float* ps0 = psi0 + t * 1600;
  __syncthreads();
  for (int o = tid; o < 1600; o += NTHR) {
    int i = o / 40, j = o - 40 * i;
    float p = ps0[o];
    float2 v = A[i * 41 + j];
    A[i * 41 + j] = make_float2(v.x * p, v.y * p);
  }
  __syncthreads();
  radix40<true>(A, T40, tw40, tid);
  for (int o = tid; o < 1600; o += NTHR) {
    int i = o / 40, j = o - 40 * i;
    float2 z = A[i * 41 + j];
    A[i * 41 + j] = make_float2(sqrtf(fmaf(z.x, z.x, z.y * z.y)), 0.f);
  }
  __syncthreads();
  radix40<false>(A, T40, tw40, tid);

  // ---- S1a fold4 -> accumulate into P (pack with rotated S1b), one ifft10
  for (int q = tid; q < 100; q += NTHR) {
    int q1 = q / 10, q2 = q - 10 * q1;
    int base = q1 * 41 + q2;
    float re = 0.f, im = 0.f;
#pragma unroll
    for (int a2 = 0; a2 < 4; ++a2) {
      float4 pf = ph0f4[q * 4 + a2];
      float2 v0 = A[base + a2 * 410];
      float2 v1 = A[base + a2 * 410 + 10];
      float2 v2 = A[base + a2 * 410 + 20];
      float2 v3 = A[base + a2 * 410 + 30];
      re = fmaf(v0.x, pf.x, fmaf(v1.x, pf.y, fmaf(v2.x, pf.z, fmaf(v3.x, pf.w, re))));
      im = fmaf(v0.y, pf.x, fmaf(v1.y, pf.y, fmaf(v2.y, pf.z, fmaf(v3.y, pf.w, im))));
    }
    float2 prev = P[q1 * 11 + q2];
    P[q1 * 11 + q2] = make_float2(prev.x + re, prev.y + im);
  }
  __syncthreads();
  dft2dB<10, 11, 1, true, 1, 0>(P, SC1, tw10, tid);
  if (tid < 64) {
    int i = tid >> 3, j = tid & 7;
    float2 v = P[(i + 1) * 11 + (j + 1)];
    fb[(1 + t) * 64 + tid] = v.x;   // S1a
    fb[(9 + t) * 64 + tid] = v.y;   // S1b
  }
  // RACE FIX: order-2 fold writes CI over P's floats; the tid<64 P-reads above
  // must complete first.
  __syncthreads();

  // ---- order 2, batch-8: folds -> ifft20 x8 -> fwd(mag-pack) x4 -> lowpass -> ifft10 x4
  for (int u = tid; u < 3200; u += NTHR) {
    int ch = u / 400, q = u - 400 * ch;
    int q1 = q / 20, q2 = q - 20 * q1;
    int base = q1 * 41 + q2;
    float4 pf = ps1f4[ch * 400 + q];
    float2 v0 = A[base], v1 = A[base + 20], v2 = A[base + 820], v3 = A[base + 840];
    float re = fmaf(v0.x, pf.x, fmaf(v1.x, pf.y, fmaf(v2.x, pf.z, v3.x * pf.w)));
    float im = fmaf(v0.y, pf.x, fmaf(v1.y, pf.y, fmaf(v2.y, pf.z, v3.y * pf.w)));
    int o = ch * 420 + q1 * 21 + q2;
    CR[o] = re; CI[o] = im;
  }
  __syncthreads();
  fused20_pass<true, 8, false, false>(CR, CI, tid);   // inverse rows
  __syncthreads();
  fused20_pass<true, 8, true, true>(CR, CI, tid);     // inverse cols + 1/400
  __syncthreads();
  fwd20_rows_mag(CR, CI, FR, FI, tid);                // |.| pairs + fwd rows (A region dead)
  __syncthreads();
  fused20_pass<false, 4, false, true>(FR, FI, tid);   // fwd cols
  __syncthreads();
  for (int u = tid; u < 400; u += NTHR) {
    int p = u / 100, q = u - 100 * p;
    int q1 = q / 10, q2 = q - 10 * q1;
    int base = p * 420 + q1 * 21 + q2;
    float4 pf = ph1f4[q];
    float re = fmaf(FR[base], pf.x, fmaf(FR[base + 10], pf.y,
               fmaf(FR[base + 210], pf.z, FR[base + 220] * pf.w)));
    float im = fmaf(FI[base], pf.x, fmaf(FI[base + 10], pf.y,
               fmaf(FI[base + 210], pf.z, FI[base + 220] * pf.w)));
    P4[p * 110 + q1 * 11 + q2] = make_float2(re, im);
  }
  __syncthreads();
  dft2dB<10, 11, 1, true, 4, 110>(P4, SC4, tw10, tid);
  {
    int p = tid >> 6, o = tid & 63;      // 256 = 4*64 exactly
    int i = o >> 3, j = o & 7;
    float2 v = P4[p * 110 + (i + 1) * 11 + (j + 1)];
    fb[(17 + t * 8 + 2 * p) * 64 + o] = v.x;
    fb[(17 + t * 8 + 2 * p + 1) * 64 + o] = v.y;
  }
}

// ---------- Kernel 4: BN stats over batch (8-way ILP) ----------
__global__ __launch_bounds__(NTHR) void k_bn(const float* __restrict__ f,
                                             float* __restrict__ mu,
                                             float* __restrict__ rstd) {
  int col = blockIdx.x * NTHR + threadIdx.x;
  if (col >= 15552) return;
  double s = 0.0, s2 = 0.0;
  for (int b = 0; b < 128; b += 8) {
    float v[8];
#pragma unroll
    for (int u = 0; u < 8; ++u) v[u] = f[(size_t)(b + u) * 15552 + col];
#pragma unroll
    for (int u = 0; u < 8; ++u) { s += v[u]; s2 += (double)v[u] * v[u]; }
  }
  double m = s / 128.0;
  double var = s2 / 128.0 - m * m;
  mu[col] = (float)m;
  rstd[col] = (float)(1.0 / sqrt(var + 1e-5));
}

// ---------- Kernel 5: fused BN-apply + relu + collapsed ToeplitzLike, pipelined ----------
__global__ __launch_bounds__(NTHR) void k_out(const float* __restrict__ f,
                                              const float* __restrict__ mu,
                                              const float* __restrict__ rstd,
                                              const float* __restrict__ gamma,
                                              const float* __restrict__ beta,
                                              const float* __restrict__ Gm,
                                              const float* __restrict__ Hm,
                                              float* __restrict__ out) {
  const int b = blockIdx.x;
  const int tid = threadIdx.x;
  const float* fbp = f + (size_t)b * 15552;

  __shared__ float sg[NTHR + 10];
  float acc[40];
#pragma unroll
  for (int i = 0; i < 40; ++i) acc[i] = 0.f;

  // chunk-0 prefetch
  float vcur, vtail = 0.f;
  {
    int j = tid;
    float v = (fbp[j] - mu[j]) * rstd[j] * gamma[j] + beta[j];
    vcur = v > 0.f ? v : 0.f;
    if (tid < 10) {
      int j2 = NTHR + tid;
      float v2 = (fbp[j2] - mu[j2]) * rstd[j2] * gamma[j2] + beta[j2];
      vtail = v2 > 0.f ? v2 : 0.f;
    }
  }
  for (int base = 0; base < 15552; base += NTHR) {
    sg[tid] = vcur;
    if (tid < 10) sg[NTHR + tid] = vtail;
    __syncthreads();
    // prefetch next chunk while computing this one
    float vnext = 0.f, vtn = 0.f;
    int nbase = base + NTHR;
    if (nbase < 15552) {
      int j = nbase + tid;
      if (j < 15552) {
        float v = (fbp[j] - mu[j]) * rstd[j] * gamma[j] + beta[j];
        vnext = v > 0.f ? v : 0.f;
      }
      if (tid < 10) {
        int j2 = nbase + NTHR + tid;
        if (j2 < 15552) {
          float v2 = (fbp[j2] - mu[j2]) * rstd[j2] * gamma[j2] + beta[j2];
          vtn = v2 > 0.f ? v2 : 0.f;
        }
      }
    }
    int j = base + tid;
    if (j < 15552) {
      float h[4];
#pragma unroll
      for (int r = 0; r < 4; ++r) h[r] = Hm[r * 15552 + j];
#pragma unroll
      for (int m = 0; m < 10; ++m) {
        float gv = sg[tid + m];
#pragma unroll
        for (int r = 0; r < 4; ++r) acc[r * 10 + m] = fmaf(h[r], gv, acc[r * 10 + m]);
      }
    }
    __syncthreads();
    vcur = vnext; vtail = vtn;
  }
#pragma unroll
  for (int i = 0; i < 40; ++i)
    for (int off = 32; off > 0; off >>= 1)
      acc[i] += __shfl_down(acc[i], off);

  __shared__ float red[4][40];
  __shared__ float Tm[40];
  int lane = tid & 63, w = tid >> 6;
  if (lane == 0) {
#pragma unroll
    for (int i = 0; i < 40; ++i) red[w][i] = acc[i];
  }
  __syncthreads();
  if (tid < 40) Tm[tid] = red[0][tid] + red[1][tid] + red[2][tid] + red[3][tid];
  __syncthreads();
  if (tid < 10) {
    float y = 0.f;
    for (int r = 0; r < 4; ++r)
      for (int m = 0; m <= tid; ++m)
        y += Gm[r * 15552 + (tid - m)] * Tm[r * 10 + m];
    out[b * 10 + tid] = y;
  }
}

extern "C" void kernel_launch(void* const* d_in, const int* in_sizes, int n_in,
                              void* d_out, int out_size, void* d_ws, size_t ws_size,
                              hipStream_t stream) {
  (void)in_sizes; (void)n_in; (void)out_size; (void)ws_size;
  const float* x     = (const float*)d_in[0];   // (128,3,32,32)
  const float* gamma = (const float*)d_in[1];   // (15552,)
  const float* beta  = (const float*)d_in[2];   // (15552,)
  const float* G     = (const float*)d_in[3];   // (4,15552)
  const float* H     = (const float*)d_in[4];   // (4,15552)
  float* out = (float*)d_out;                   // (128,10)

  float* ws   = (float*)d_ws;
  float* filt = ws;                         // 27600
  float* xf   = filt + 27600;               // 384*1600*2 = 1228800
  float* f    = xf + 1228800;               // 128*15552 = 1990656
  float* mu   = f + 1990656;                // 15552
  float* rstd = mu + 15552;                 // 15552

  k_filters<<<17, NTHR, 0, stream>>>(filt);
  k_fftx<<<384, NTHR, 0, stream>>>(x, filt, (float2*)xf, f);
  k_main<<<3072, NTHR, 0, stream>>>((const float2*)xf, filt, f);
  k_bn<<<61, NTHR, 0, stream>>>(f, mu, rstd);
  k_out<<<128, NTHR, 0, stream>>>(f, mu, rstd, gamma, beta, G, H, out);
}